// Round 1
// baseline (1363.657 us; speedup 1.0000x reference)
//
#include <hip/hip_runtime.h>
#include <math.h>

#define NN   20000      // nodes
#define NE   640000     // edges
#define NPADN 20480     // padded node count for scan (multiple of 4096)
#define HH   128        // hidden
#define GG   64         // groups
#define INF_ 1e30f

// ---------------- block reduction helpers (blockDim == 128) ----------------
__device__ __forceinline__ float blk_sum(float v, float* red) {
#pragma unroll
  for (int off = 32; off >= 1; off >>= 1) v += __shfl_xor(v, off);
  if ((threadIdx.x & 63) == 0) red[threadIdx.x >> 6] = v;
  __syncthreads();
  float r = red[0] + red[1];
  __syncthreads();
  return r;
}
__device__ __forceinline__ float blk_max(float v, float* red) {
#pragma unroll
  for (int off = 32; off >= 1; off >>= 1) v = fmaxf(v, __shfl_xor(v, off));
  if ((threadIdx.x & 63) == 0) red[threadIdx.x >> 6] = v;
  __syncthreads();
  float r = fmaxf(red[0], red[1]);
  __syncthreads();
  return r;
}

// ---------------- CSR construction ----------------
__global__ void zero_ints(int* p, int n) {
  int i = blockIdx.x * 256 + threadIdx.x;
  if (i < n) p[i] = 0;
}

__global__ void hist_kernel(const int* __restrict__ dst, int* __restrict__ deg) {
  int e = blockIdx.x * 256 + threadIdx.x;
  if (e < NE) atomicAdd(&deg[dst[e]], 1);
}

// single-block scan: 256 threads x 16 elems/thread/tile, 5 tiles over NPADN
__global__ void scan_kernel(const int* __restrict__ deg, int* __restrict__ row_start,
                            int* __restrict__ cursor) {
  __shared__ int buf[256];
  __shared__ int carry_s;
  int t = threadIdx.x;
  if (t == 0) carry_s = 0;
  __syncthreads();
  for (int base = 0; base < NPADN; base += 4096) {
    int idx0 = base + t * 16;
    int4 a = *(const int4*)&deg[idx0];
    int4 b = *(const int4*)&deg[idx0 + 4];
    int4 c = *(const int4*)&deg[idx0 + 8];
    int4 d = *(const int4*)&deg[idx0 + 12];
    int x[16] = {a.x,a.y,a.z,a.w, b.x,b.y,b.z,b.w, c.x,c.y,c.z,c.w, d.x,d.y,d.z,d.w};
    int pre[16];
    int run = 0;
#pragma unroll
    for (int j = 0; j < 16; j++) { pre[j] = run; run += x[j]; }
    buf[t] = run;
    __syncthreads();
    int sum = run;
#pragma unroll
    for (int off = 1; off < 256; off <<= 1) {
      int addv = (t >= off) ? buf[t - off] : 0;
      __syncthreads();
      sum += addv;
      buf[t] = sum;
      __syncthreads();
    }
    int excl = sum - run;
    int carry = carry_s;
    int basev = carry + excl;
#pragma unroll
    for (int j = 0; j < 16; j++) {
      int i = idx0 + j;
      if (i < NN) { row_start[i] = basev + pre[j]; cursor[i] = basev + pre[j]; }
    }
    __syncthreads();
    if (t == 255) carry_s = carry + sum;
    __syncthreads();
  }
  if (t == 0) row_start[NN] = carry_s;
}

__global__ void scatter_kernel(const int* __restrict__ dst, const int* __restrict__ src,
                               int* __restrict__ cursor, int* __restrict__ eidx,
                               int* __restrict__ srcs) {
  int e = blockIdx.x * 256 + threadIdx.x;
  if (e < NE) {
    int d = dst[e];
    int p = atomicAdd(&cursor[d], 1);
    eidx[p] = e;
    srcs[p] = src[e];
  }
}

// ---------------- generic node GEMM: [8 nodes/block] x (K -> NCHUNK*128) ----------------
// X rows are the concat of up to 4 pieces. Weight chunk cc>0 can skip rows
// (row = j + skip_amt for j >= skip_at) to address K2w/V2w layouts.
template <int K, int NCHUNK, bool DO_LN, bool DO_LOGIT>
__global__ __launch_bounds__(128) void node_gemm(
    const float* __restrict__ x0, int l0, const float* __restrict__ x1, int l1,
    const float* __restrict__ x2, int l2, const float* __restrict__ x3, int l3,
    const float* __restrict__ w0, const float* __restrict__ w1, const float* __restrict__ w2,
    int skip_at, int skip_amt,
    const float* __restrict__ b0, const float* __restrict__ b1, const float* __restrict__ b2,
    float* __restrict__ out0, float* __restrict__ out1, float* __restrict__ out2,
    const float* __restrict__ ln_g, const float* __restrict__ ln_b,
    const float* __restrict__ gate_w, const float* __restrict__ gate_b,
    float* __restrict__ logit) {
  __shared__ float xs[8][K];
  __shared__ float red[2];
  int tid = threadIdx.x;
  int n0 = blockIdx.x * 8;

  for (int idx = tid; idx < 8 * K; idx += 128) {
    int nn = idx / K, k = idx % K;
    int n = n0 + nn;
    float v;
    if (k < l0)               v = x0[n * l0 + k];
    else if (k < l0 + l1)     v = x1[n * l1 + (k - l0)];
    else if (k < l0 + l1 + l2) v = x2[n * l2 + (k - l0 - l1)];
    else                      v = x3[n * l3 + (k - l0 - l1 - l2)];
    xs[nn][k] = v;
  }
  __syncthreads();

  for (int cc = 0; cc < NCHUNK; cc++) {
    const float* W = (cc == 0) ? w0 : ((cc == 1) ? w1 : w2);
    const float* B = (cc == 0) ? b0 : ((cc == 1) ? b1 : b2);
    float acc[8];
    float bv = B[tid];
#pragma unroll
    for (int nn = 0; nn < 8; nn++) acc[nn] = bv;

    for (int j0 = 0; j0 < K; j0 += 4) {
      float w[4];
#pragma unroll
      for (int jj = 0; jj < 4; jj++) {
        int j = j0 + jj;
        int row = (cc > 0 && j >= skip_at) ? (j + skip_amt) : j;
        w[jj] = W[row * 128 + tid];
      }
#pragma unroll
      for (int nn = 0; nn < 8; nn++) {
        float4 xv = *(const float4*)&xs[nn][j0];
        acc[nn] = fmaf(xv.x, w[0], acc[nn]);
        acc[nn] = fmaf(xv.y, w[1], acc[nn]);
        acc[nn] = fmaf(xv.z, w[2], acc[nn]);
        acc[nn] = fmaf(xv.w, w[3], acc[nn]);
      }
    }

    if (!DO_LN) {
      float* outp = (cc == 0) ? out0 : ((cc == 1) ? out1 : out2);
#pragma unroll
      for (int nn = 0; nn < 8; nn++) outp[(n0 + nn) * 128 + tid] = acc[nn];
    } else {
#pragma unroll 1
      for (int nn = 0; nn < 8; nn++) {
        float val = acc[nn];
        float mean = blk_sum(val, red) * (1.0f / 128.0f);
        float dv = val - mean;
        float var = blk_sum(dv * dv, red) * (1.0f / 128.0f);
        float hv = dv * (1.0f / sqrtf(var + 1e-5f)) * ln_g[tid] + ln_b[tid];
        out0[(n0 + nn) * 128 + tid] = hv;
        if (DO_LOGIT) {
          float lg = blk_sum(hv * gate_w[tid], red);
          if (tid == 0) logit[n0 + nn] = lg + gate_b[0];
        }
      }
    }
  }
}

// ---------------- fused edge attention (per-dst online softmax) ----------------
// thread = channel (128), 4 dst nodes per block. Edge-level projection
// ke = eh[e] @ Wk3 computed on the fly with weight columns held in VGPRs.
__global__ __launch_bounds__(128) void edge_attn(
    const float* __restrict__ eh,
    const float* __restrict__ Wk3, const float* __restrict__ Wv3,  // 64 x 128 each
    const float* __restrict__ qn, const float* __restrict__ kn, const float* __restrict__ vn,
    const int* __restrict__ row_start, const int* __restrict__ eidx,
    const int* __restrict__ srcs, float* __restrict__ hn) {
  __shared__ float ehs[8][64];
  int tid = threadIdx.x;

  float wk[64], wv[64];
#pragma unroll
  for (int j = 0; j < 64; j++) {
    wk[j] = Wk3[j * 128 + tid];
    wv[j] = Wv3[j * 128 + tid];
  }

  int nbase = blockIdx.x * 4;
  for (int nn = 0; nn < 4; nn++) {
    int n = nbase + nn;
    int rs = row_start[n], re = row_start[n + 1];
    float qv = qn[n * 128 + tid];
    float m = -INF_, s = 0.0f, hacc = 0.0f;

    for (int t0 = rs; t0 < re; t0 += 8) {
      int cnt = min(8, re - t0);
      if (tid < cnt * 16) {
        int slot = tid >> 4, l = tid & 15;
        int e = eidx[t0 + slot];
        *(float4*)&ehs[slot][l * 4] = *(const float4*)&eh[(size_t)e * 64 + l * 4];
      }
      __syncthreads();
      for (int i = 0; i < cnt; i++) {
        int sv = srcs[t0 + i];
        float knv = kn[sv * 128 + tid];
        float vnv = vn[sv * 128 + tid];
        float ke = 0.0f, ve = 0.0f;
#pragma unroll
        for (int j4 = 0; j4 < 16; j4++) {
          float4 x = *(const float4*)&ehs[i][j4 * 4];
          ke = fmaf(x.x, wk[4 * j4 + 0], ke);
          ke = fmaf(x.y, wk[4 * j4 + 1], ke);
          ke = fmaf(x.z, wk[4 * j4 + 2], ke);
          ke = fmaf(x.w, wk[4 * j4 + 3], ke);
          ve = fmaf(x.x, wv[4 * j4 + 0], ve);
          ve = fmaf(x.y, wv[4 * j4 + 1], ve);
          ve = fmaf(x.z, wv[4 * j4 + 2], ve);
          ve = fmaf(x.w, wv[4 * j4 + 3], ve);
        }
        float a = qv * (knv + ke);
        float vval = vnv + ve;
        float mn = fmaxf(m, a);
        float scale = __expf(m - mn);
        float p = __expf(a - mn);
        s = s * scale + p;
        hacc = hacc * scale + p * vval;
        m = mn;
      }
      __syncthreads();
    }
    hn[n * 128 + tid] = (re > rs) ? (hacc / s) : 0.0f;
  }
}

// ---------------- readout ----------------
__global__ void gstart_kernel(const int* __restrict__ gid, int* __restrict__ gstart) {
  int g = threadIdx.x;
  if (g <= GG) {
    int lo = 0, hi = NN;  // first i with gid[i] >= g
    while (lo < hi) {
      int mid = (lo + hi) >> 1;
      if (gid[mid] < g) lo = mid + 1; else hi = mid;
    }
    gstart[g] = lo;
  }
}

__global__ __launch_bounds__(128) void readout_kernel(
    const float* __restrict__ h1, const float* __restrict__ logit,
    const int* __restrict__ gstart, float* __restrict__ out) {
  __shared__ float red[2];
  int g = blockIdx.x, tid = threadIdx.x;
  int s0 = gstart[g], s1 = gstart[g + 1];

  float mx = -INF_;
  for (int i = s0 + tid; i < s1; i += 128) mx = fmaxf(mx, logit[i]);
  mx = blk_max(mx, red);

  float sum = 0.0f;
  for (int i = s0 + tid; i < s1; i += 128) sum += __expf(logit[i] - mx);
  sum = blk_sum(sum, red);

  float acc = 0.0f;
  for (int i = s0; i < s1; i++) {
    float w = __expf(logit[i] - mx);
    acc = fmaf(w, h1[i * 128 + tid], acc);
  }
  out[g * 128 + tid] = (s1 > s0) ? (acc / sum) : 0.0f;
}

// ---------------- launcher ----------------
extern "C" void kernel_launch(void* const* d_in, const int* in_sizes, int n_in,
                              void* d_out, int out_size, void* d_ws, size_t ws_size,
                              hipStream_t stream) {
  const float* kind  = (const float*)d_in[0];
  const float* ntype = (const float*)d_in[1];
  const float* eh    = (const float*)d_in[2];
  const float* Qw = (const float*)d_in[3];  const float* Qb = (const float*)d_in[4];
  const float* Kw = (const float*)d_in[5];  const float* Kb = (const float*)d_in[6];
  const float* Vw = (const float*)d_in[7];  const float* Vb = (const float*)d_in[8];
  const float* Ww = (const float*)d_in[9];  const float* Wb = (const float*)d_in[10];
  const float* Q2w = (const float*)d_in[11]; const float* Q2b = (const float*)d_in[12];
  const float* K2w = (const float*)d_in[13]; const float* K2b = (const float*)d_in[14];
  const float* V2w = (const float*)d_in[15]; const float* V2b = (const float*)d_in[16];
  const float* W2w = (const float*)d_in[17]; const float* W2b = (const float*)d_in[18];
  const float* ln_g = (const float*)d_in[19]; const float* ln_b = (const float*)d_in[20];
  const float* gate_w = (const float*)d_in[21]; const float* gate_b = (const float*)d_in[22];
  const int* src = (const int*)d_in[23];
  const int* dst = (const int*)d_in[24];
  const int* gid = (const int*)d_in[25];
  float* out = (float*)d_out;

  char* wp = (char*)d_ws;
  auto alloc = [&](size_t bytes) {
    void* p = (void*)wp;
    wp += (bytes + 255) & ~(size_t)255;
    return p;
  };
  float* q1  = (float*)alloc((size_t)NN * HH * 4);
  float* k1n = (float*)alloc((size_t)NN * HH * 4);
  float* v1n = (float*)alloc((size_t)NN * HH * 4);
  float* hn  = (float*)alloc((size_t)NN * HH * 4);
  float* h   = (float*)alloc((size_t)NN * HH * 4);
  float* q2  = (float*)alloc((size_t)NN * HH * 4);
  float* k2n = (float*)alloc((size_t)NN * HH * 4);
  float* v2n = (float*)alloc((size_t)NN * HH * 4);
  float* hn2 = (float*)alloc((size_t)NN * HH * 4);
  float* h1  = (float*)alloc((size_t)NN * HH * 4);
  float* logit = (float*)alloc((size_t)NN * 4);
  int* deg       = (int*)alloc((size_t)NPADN * 4);
  int* row_start = (int*)alloc((size_t)(NN + 1) * 4);
  int* cursor    = (int*)alloc((size_t)NN * 4);
  int* eidx      = (int*)alloc((size_t)NE * 4);
  int* srcs      = (int*)alloc((size_t)NE * 4);
  int* gstart    = (int*)alloc((size_t)(GG + 1) * 4);

  const int NOSKIP = 1 << 30;

  // CSR
  zero_ints<<<(NPADN + 255) / 256, 256, 0, stream>>>(deg, NPADN);
  hist_kernel<<<(NE + 255) / 256, 256, 0, stream>>>(dst, deg);
  scan_kernel<<<1, 256, 0, stream>>>(deg, row_start, cursor);
  scatter_kernel<<<(NE + 255) / 256, 256, 0, stream>>>(dst, src, cursor, eidx, srcs);

  // layer 1: q/k_node/v_node  ([kind|ntype] @ {Qw, Kw[0:128], Vw[0:128]})
  node_gemm<128, 3, false, false><<<NN / 8, 128, 0, stream>>>(
      kind, 64, ntype, 64, nullptr, 0, nullptr, 0,
      Qw, Kw, Vw, NOSKIP, 0, Qb, Kb, Vb,
      q1, k1n, v1n, nullptr, nullptr, nullptr, nullptr, nullptr);

  edge_attn<<<NN / 4, 128, 0, stream>>>(eh, Kw + 128 * 128, Vw + 128 * 128,
                                        q1, k1n, v1n, row_start, eidx, srcs, hn);

  // h = LN([hn|kind|ntype] @ Ww + Wb)
  node_gemm<256, 1, true, false><<<NN / 8, 128, 0, stream>>>(
      hn, 128, kind, 64, ntype, 64, nullptr, 0,
      Ww, nullptr, nullptr, NOSKIP, 0, Wb, nullptr, nullptr,
      h, nullptr, nullptr, ln_g, ln_b, nullptr, nullptr, nullptr);

  // layer 2: q2/k2_node/v2_node  ([kind|ntype|h] @ {Q2w, K2w rows(0:128,192:320), V2w same})
  node_gemm<256, 3, false, false><<<NN / 8, 128, 0, stream>>>(
      kind, 64, ntype, 64, h, 128, nullptr, 0,
      Q2w, K2w, V2w, 128, 64, Q2b, K2b, V2b,
      q2, k2n, v2n, nullptr, nullptr, nullptr, nullptr, nullptr);

  edge_attn<<<NN / 4, 128, 0, stream>>>(eh, K2w + 128 * 128, V2w + 128 * 128,
                                        q2, k2n, v2n, row_start, eidx, srcs, hn2);

  // h1 = LN([hn2|h|kind|ntype] @ W2w + W2b), fused gate logit
  node_gemm<384, 1, true, true><<<NN / 8, 128, 0, stream>>>(
      hn2, 128, h, 128, kind, 64, ntype, 64,
      W2w, nullptr, nullptr, NOSKIP, 0, W2b, nullptr, nullptr,
      h1, nullptr, nullptr, ln_g, ln_b, gate_w, gate_b, logit);

  // readout
  gstart_kernel<<<1, 128, 0, stream>>>(gid, gstart);
  readout_kernel<<<GG, 128, 0, stream>>>(h1, logit, gstart, out);
}

// Round 2
// 1072.681 us; speedup vs baseline: 1.2713x; 1.2713x over previous
//
#include <hip/hip_runtime.h>
#include <math.h>

#define NN   20000      // nodes
#define NE   640000     // edges
#define NPADN 20480     // padded node count for scan (multiple of 4096)
#define HH   128        // hidden
#define GG   64         // groups
#define INF_ 1e30f

typedef unsigned short u16;
typedef short bf16x8 __attribute__((ext_vector_type(8)));
typedef float f32x4 __attribute__((ext_vector_type(4)));

__device__ __forceinline__ u16 f2bf(float x) {
  union { float f; unsigned u; } c; c.f = x;
  unsigned r = c.u + 0x7FFFu + ((c.u >> 16) & 1u);
  return (u16)(r >> 16);
}
__device__ __forceinline__ float bf2f(u16 u) {
  union { unsigned u; float f; } c; c.u = ((unsigned)u) << 16;
  return c.f;
}

// ---------------- block reduction helpers (blockDim == 128) ----------------
__device__ __forceinline__ float blk_sum(float v, float* red) {
#pragma unroll
  for (int off = 32; off >= 1; off >>= 1) v += __shfl_xor(v, off);
  if ((threadIdx.x & 63) == 0) red[threadIdx.x >> 6] = v;
  __syncthreads();
  float r = red[0] + red[1];
  __syncthreads();
  return r;
}
__device__ __forceinline__ float blk_max(float v, float* red) {
#pragma unroll
  for (int off = 32; off >= 1; off >>= 1) v = fmaxf(v, __shfl_xor(v, off));
  if ((threadIdx.x & 63) == 0) red[threadIdx.x >> 6] = v;
  __syncthreads();
  float r = fmaxf(red[0], red[1]);
  __syncthreads();
  return r;
}

// ---------------- CSR construction ----------------
__global__ void zero_ints(int* p, int n) {
  int i = blockIdx.x * 256 + threadIdx.x;
  if (i < n) p[i] = 0;
}

__global__ void hist_kernel(const int* __restrict__ dst, int* __restrict__ deg) {
  int e = blockIdx.x * 256 + threadIdx.x;
  if (e < NE) atomicAdd(&deg[dst[e]], 1);
}

__global__ void scan_kernel(const int* __restrict__ deg, int* __restrict__ row_start,
                            int* __restrict__ cursor) {
  __shared__ int buf[256];
  __shared__ int carry_s;
  int t = threadIdx.x;
  if (t == 0) carry_s = 0;
  __syncthreads();
  for (int base = 0; base < NPADN; base += 4096) {
    int idx0 = base + t * 16;
    int4 a = *(const int4*)&deg[idx0];
    int4 b = *(const int4*)&deg[idx0 + 4];
    int4 c = *(const int4*)&deg[idx0 + 8];
    int4 d = *(const int4*)&deg[idx0 + 12];
    int x[16] = {a.x,a.y,a.z,a.w, b.x,b.y,b.z,b.w, c.x,c.y,c.z,c.w, d.x,d.y,d.z,d.w};
    int pre[16];
    int run = 0;
#pragma unroll
    for (int j = 0; j < 16; j++) { pre[j] = run; run += x[j]; }
    buf[t] = run;
    __syncthreads();
    int sum = run;
#pragma unroll
    for (int off = 1; off < 256; off <<= 1) {
      int addv = (t >= off) ? buf[t - off] : 0;
      __syncthreads();
      sum += addv;
      buf[t] = sum;
      __syncthreads();
    }
    int excl = sum - run;
    int carry = carry_s;
    int basev = carry + excl;
#pragma unroll
    for (int j = 0; j < 16; j++) {
      int i = idx0 + j;
      if (i < NN) { row_start[i] = basev + pre[j]; cursor[i] = basev + pre[j]; }
    }
    __syncthreads();
    if (t == 255) carry_s = carry + sum;
    __syncthreads();
  }
  if (t == 0) row_start[NN] = carry_s;
}

__global__ void scatter_kernel(const int* __restrict__ dst, const int* __restrict__ src,
                               int* __restrict__ cursor, int* __restrict__ eidx,
                               int* __restrict__ srcs) {
  int e = blockIdx.x * 256 + threadIdx.x;
  if (e < NE) {
    int d = dst[e];
    int p = atomicAdd(&cursor[d], 1);
    eidx[p] = e;
    srcs[p] = src[e];
  }
}

// ---------------- weight transpose: W[64][128] -> Wt[128][64] bf16 ----------------
__global__ void wtrans(const float* __restrict__ W, u16* __restrict__ Wt) {
  int i = blockIdx.x * 256 + threadIdx.x;
  if (i < 128 * 64) {
    int c = i >> 6, k = i & 63;
    Wt[i] = f2bf(W[k * 128 + c]);
  }
}

// ---------------- generic node GEMM: [8 nodes/block] x (K -> NCHUNK*128) ----------------
template <int K, int NCHUNK, bool DO_LN, bool DO_LOGIT>
__global__ __launch_bounds__(128) void node_gemm(
    const float* __restrict__ x0, int l0, const float* __restrict__ x1, int l1,
    const float* __restrict__ x2, int l2, const float* __restrict__ x3, int l3,
    const float* __restrict__ w0, const float* __restrict__ w1, const float* __restrict__ w2,
    int skip_at, int skip_amt,
    const float* __restrict__ b0, const float* __restrict__ b1, const float* __restrict__ b2,
    float* __restrict__ out0, float* __restrict__ out1, float* __restrict__ out2,
    const float* __restrict__ ln_g, const float* __restrict__ ln_b,
    const float* __restrict__ gate_w, const float* __restrict__ gate_b,
    float* __restrict__ logit) {
  __shared__ float xs[8][K];
  __shared__ float red[2];
  int tid = threadIdx.x;
  int n0 = blockIdx.x * 8;

  for (int idx = tid; idx < 8 * K; idx += 128) {
    int nn = idx / K, k = idx % K;
    int n = n0 + nn;
    float v;
    if (k < l0)               v = x0[n * l0 + k];
    else if (k < l0 + l1)     v = x1[n * l1 + (k - l0)];
    else if (k < l0 + l1 + l2) v = x2[n * l2 + (k - l0 - l1)];
    else                      v = x3[n * l3 + (k - l0 - l1 - l2)];
    xs[nn][k] = v;
  }
  __syncthreads();

  for (int cc = 0; cc < NCHUNK; cc++) {
    const float* W = (cc == 0) ? w0 : ((cc == 1) ? w1 : w2);
    const float* B = (cc == 0) ? b0 : ((cc == 1) ? b1 : b2);
    float acc[8];
    float bv = B[tid];
#pragma unroll
    for (int nn = 0; nn < 8; nn++) acc[nn] = bv;

    for (int j0 = 0; j0 < K; j0 += 4) {
      float w[4];
#pragma unroll
      for (int jj = 0; jj < 4; jj++) {
        int j = j0 + jj;
        int row = (cc > 0 && j >= skip_at) ? (j + skip_amt) : j;
        w[jj] = W[row * 128 + tid];
      }
#pragma unroll
      for (int nn = 0; nn < 8; nn++) {
        float4 xv = *(const float4*)&xs[nn][j0];
        acc[nn] = fmaf(xv.x, w[0], acc[nn]);
        acc[nn] = fmaf(xv.y, w[1], acc[nn]);
        acc[nn] = fmaf(xv.z, w[2], acc[nn]);
        acc[nn] = fmaf(xv.w, w[3], acc[nn]);
      }
    }

    if (!DO_LN) {
      float* outp = (cc == 0) ? out0 : ((cc == 1) ? out1 : out2);
#pragma unroll
      for (int nn = 0; nn < 8; nn++) outp[(n0 + nn) * 128 + tid] = acc[nn];
    } else {
#pragma unroll 1
      for (int nn = 0; nn < 8; nn++) {
        float val = acc[nn];
        float mean = blk_sum(val, red) * (1.0f / 128.0f);
        float dv = val - mean;
        float var = blk_sum(dv * dv, red) * (1.0f / 128.0f);
        float hv = dv * (1.0f / sqrtf(var + 1e-5f)) * ln_g[tid] + ln_b[tid];
        out0[(n0 + nn) * 128 + tid] = hv;
        if (DO_LOGIT) {
          float lg = blk_sum(hv * gate_w[tid], red);
          if (tid == 0) logit[n0 + nn] = lg + gate_b[0];
        }
      }
    }
  }
}

// ---------------- phase A: edge projection GEMM (MFMA bf16) ----------------
// Computes ke[p] = eh[eidx[p]] @ WkT^T, ve[p] = eh[eidx[p]] @ WvT^T for all
// edges p in CSR order, stored bf16 [E][128].
// MFMA orientation: D[m=channel][n=edge], A = Wt (c-major, [128][64]),
// B = edge tile. Both operands use lane k-map (lane>>4)*8+j (contiguous 16B)
// -> correct for any internal k-permutation. D: col=lane&15 (edge),
// row=(lane>>4)*4+reg (channel) [m89-verified].
#define EG_BLOCKS 1280
__global__ __launch_bounds__(256, 2) void edge_gemm(
    const float* __restrict__ eh, const int* __restrict__ eidx,
    const u16* __restrict__ WtK, const u16* __restrict__ WtV,
    u16* __restrict__ ke, u16* __restrict__ ve) {
  int lane = threadIdx.x & 63;
  int er = lane & 15, kg = lane >> 4;
  int wglob = blockIdx.x * 4 + (threadIdx.x >> 6);

  // weight A-fragments, held for the whole kernel
  bf16x8 aK[8][2], aV[8][2];
#pragma unroll
  for (int mt = 0; mt < 8; mt++)
#pragma unroll
    for (int ks = 0; ks < 2; ks++) {
      int off = (mt * 16 + er) * 64 + ks * 32 + kg * 8;
      aK[mt][ks] = *(const bf16x8*)&WtK[off];
      aV[mt][ks] = *(const bf16x8*)&WtV[off];
    }

  for (int tile = wglob; tile < NE / 16; tile += EG_BLOCKS * 4) {
    int ebase = tile * 16;
    int e = eidx[ebase + er];
    const float* ehrow = eh + (size_t)e * 64;
    bf16x8 bE[2];
#pragma unroll
    for (int ks = 0; ks < 2; ks++) {
      float4 x0 = *(const float4*)&ehrow[ks * 32 + kg * 8];
      float4 x1 = *(const float4*)&ehrow[ks * 32 + kg * 8 + 4];
      union { u16 u[8]; bf16x8 v; } pk;
      pk.u[0] = f2bf(x0.x); pk.u[1] = f2bf(x0.y); pk.u[2] = f2bf(x0.z); pk.u[3] = f2bf(x0.w);
      pk.u[4] = f2bf(x1.x); pk.u[5] = f2bf(x1.y); pk.u[6] = f2bf(x1.z); pk.u[7] = f2bf(x1.w);
      bE[ks] = pk.v;
    }

    f32x4 accK[8], accV[8];
#pragma unroll
    for (int mt = 0; mt < 8; mt++) {
      accK[mt] = (f32x4){0.f, 0.f, 0.f, 0.f};
      accV[mt] = (f32x4){0.f, 0.f, 0.f, 0.f};
    }
#pragma unroll
    for (int mt = 0; mt < 8; mt++)
#pragma unroll
      for (int ks = 0; ks < 2; ks++) {
        accK[mt] = __builtin_amdgcn_mfma_f32_16x16x32_bf16(aK[mt][ks], bE[ks], accK[mt], 0, 0, 0);
        accV[mt] = __builtin_amdgcn_mfma_f32_16x16x32_bf16(aV[mt][ks], bE[ks], accV[mt], 0, 0, 0);
      }

    int erow = (ebase + er) * 128;
#pragma unroll
    for (int mt = 0; mt < 8; mt++) {
      int c0 = mt * 16 + kg * 4;
      uint2 wk, wv;
      wk.x = (unsigned)f2bf(accK[mt][0]) | ((unsigned)f2bf(accK[mt][1]) << 16);
      wk.y = (unsigned)f2bf(accK[mt][2]) | ((unsigned)f2bf(accK[mt][3]) << 16);
      wv.x = (unsigned)f2bf(accV[mt][0]) | ((unsigned)f2bf(accV[mt][1]) << 16);
      wv.y = (unsigned)f2bf(accV[mt][2]) | ((unsigned)f2bf(accV[mt][3]) << 16);
      *(uint2*)&ke[erow + c0] = wk;
      *(uint2*)&ve[erow + c0] = wv;
    }
  }
}

// ---------------- phase B: per-dst per-channel softmax-weighted sum ----------------
// alpha[e,c] = exp(q[d,c]*k[e,c]) (no max-shift: |q*k| bounded ~30, safe in f32;
// the e/s ratio is shift-invariant). hn[d,c] = sum alpha*v / sum alpha.
__global__ __launch_bounds__(128) void attn_pass(
    const u16* __restrict__ ke, const u16* __restrict__ ve,
    const float* __restrict__ qn, const float* __restrict__ kn, const float* __restrict__ vn,
    const int* __restrict__ row_start, const int* __restrict__ srcs,
    float* __restrict__ hn) {
  int n = blockIdx.x, tid = threadIdx.x;
  int rs = row_start[n], re = row_start[n + 1];
  float qv = qn[n * 128 + tid];
  float s = 0.f, hacc = 0.f;
  int p = rs;
  for (; p + 4 <= re; p += 4) {
    float kv[4], vv[4];
#pragma unroll
    for (int i = 0; i < 4; i++) {
      int sv = srcs[p + i];
      kv[i] = kn[sv * 128 + tid] + bf2f(ke[(p + i) * 128 + tid]);
      vv[i] = vn[sv * 128 + tid] + bf2f(ve[(p + i) * 128 + tid]);
    }
#pragma unroll
    for (int i = 0; i < 4; i++) {
      float pe = __expf(qv * kv[i]);
      s += pe;
      hacc = fmaf(pe, vv[i], hacc);
    }
  }
  for (; p < re; p++) {
    int sv = srcs[p];
    float kv = kn[sv * 128 + tid] + bf2f(ke[p * 128 + tid]);
    float vv = vn[sv * 128 + tid] + bf2f(ve[p * 128 + tid]);
    float pe = __expf(qv * kv);
    s += pe;
    hacc = fmaf(pe, vv, hacc);
  }
  hn[n * 128 + tid] = (re > rs) ? (hacc / s) : 0.f;
}

// ---------------- readout ----------------
__global__ void gstart_kernel(const int* __restrict__ gid, int* __restrict__ gstart) {
  int g = threadIdx.x;
  if (g <= GG) {
    int lo = 0, hi = NN;
    while (lo < hi) {
      int mid = (lo + hi) >> 1;
      if (gid[mid] < g) lo = mid + 1; else hi = mid;
    }
    gstart[g] = lo;
  }
}

__global__ __launch_bounds__(128) void readout_kernel(
    const float* __restrict__ h1, const float* __restrict__ logit,
    const int* __restrict__ gstart, float* __restrict__ out) {
  __shared__ float red[2];
  int g = blockIdx.x, tid = threadIdx.x;
  int s0 = gstart[g], s1 = gstart[g + 1];

  float mx = -INF_;
  for (int i = s0 + tid; i < s1; i += 128) mx = fmaxf(mx, logit[i]);
  mx = blk_max(mx, red);

  float sum = 0.0f;
  for (int i = s0 + tid; i < s1; i += 128) sum += __expf(logit[i] - mx);
  sum = blk_sum(sum, red);

  float acc = 0.0f;
  for (int i = s0; i < s1; i++) {
    float w = __expf(logit[i] - mx);
    acc = fmaf(w, h1[i * 128 + tid], acc);
  }
  out[g * 128 + tid] = (s1 > s0) ? (acc / sum) : 0.0f;
}

// ---------------- launcher ----------------
extern "C" void kernel_launch(void* const* d_in, const int* in_sizes, int n_in,
                              void* d_out, int out_size, void* d_ws, size_t ws_size,
                              hipStream_t stream) {
  const float* kind  = (const float*)d_in[0];
  const float* ntype = (const float*)d_in[1];
  const float* eh    = (const float*)d_in[2];
  const float* Qw = (const float*)d_in[3];  const float* Qb = (const float*)d_in[4];
  const float* Kw = (const float*)d_in[5];  const float* Kb = (const float*)d_in[6];
  const float* Vw = (const float*)d_in[7];  const float* Vb = (const float*)d_in[8];
  const float* Ww = (const float*)d_in[9];  const float* Wb = (const float*)d_in[10];
  const float* Q2w = (const float*)d_in[11]; const float* Q2b = (const float*)d_in[12];
  const float* K2w = (const float*)d_in[13]; const float* K2b = (const float*)d_in[14];
  const float* V2w = (const float*)d_in[15]; const float* V2b = (const float*)d_in[16];
  const float* W2w = (const float*)d_in[17]; const float* W2b = (const float*)d_in[18];
  const float* ln_g = (const float*)d_in[19]; const float* ln_b = (const float*)d_in[20];
  const float* gate_w = (const float*)d_in[21]; const float* gate_b = (const float*)d_in[22];
  const int* src = (const int*)d_in[23];
  const int* dst = (const int*)d_in[24];
  const int* gid = (const int*)d_in[25];
  float* out = (float*)d_out;

  char* wp = (char*)d_ws;
  auto alloc = [&](size_t bytes) {
    void* p = (void*)wp;
    wp += (bytes + 255) & ~(size_t)255;
    return p;
  };
  u16* ke = (u16*)alloc((size_t)NE * HH * 2);
  u16* ve = (u16*)alloc((size_t)NE * HH * 2);
  float* qA = (float*)alloc((size_t)NN * HH * 4);
  float* kA = (float*)alloc((size_t)NN * HH * 4);
  float* vA = (float*)alloc((size_t)NN * HH * 4);
  float* hn = (float*)alloc((size_t)NN * HH * 4);
  float* h  = (float*)alloc((size_t)NN * HH * 4);
  float* h1 = (float*)alloc((size_t)NN * HH * 4);
  float* logit = (float*)alloc((size_t)NN * 4);
  u16* WtK1 = (u16*)alloc((size_t)128 * 64 * 2);
  u16* WtV1 = (u16*)alloc((size_t)128 * 64 * 2);
  u16* WtK2 = (u16*)alloc((size_t)128 * 64 * 2);
  u16* WtV2 = (u16*)alloc((size_t)128 * 64 * 2);
  int* deg       = (int*)alloc((size_t)NPADN * 4);
  int* row_start = (int*)alloc((size_t)(NN + 1) * 4);
  int* cursor    = (int*)alloc((size_t)NN * 4);
  int* eidx      = (int*)alloc((size_t)NE * 4);
  int* srcs      = (int*)alloc((size_t)NE * 4);
  int* gstart    = (int*)alloc((size_t)(GG + 1) * 4);

  const int NOSKIP = 1 << 30;

  // CSR
  zero_ints<<<(NPADN + 255) / 256, 256, 0, stream>>>(deg, NPADN);
  hist_kernel<<<(NE + 255) / 256, 256, 0, stream>>>(dst, deg);
  scan_kernel<<<1, 256, 0, stream>>>(deg, row_start, cursor);
  scatter_kernel<<<(NE + 255) / 256, 256, 0, stream>>>(dst, src, cursor, eidx, srcs);

  // weight transposes for edge GEMMs (rows 128..191 = eh part of K/V weights)
  wtrans<<<32, 256, 0, stream>>>(Kw + 128 * 128, WtK1);
  wtrans<<<32, 256, 0, stream>>>(Vw + 128 * 128, WtV1);
  wtrans<<<32, 256, 0, stream>>>(K2w + 128 * 128, WtK2);
  wtrans<<<32, 256, 0, stream>>>(V2w + 128 * 128, WtV2);

  // ---- layer 1 ----
  node_gemm<128, 3, false, false><<<NN / 8, 128, 0, stream>>>(
      kind, 64, ntype, 64, nullptr, 0, nullptr, 0,
      Qw, Kw, Vw, NOSKIP, 0, Qb, Kb, Vb,
      qA, kA, vA, nullptr, nullptr, nullptr, nullptr, nullptr);

  edge_gemm<<<EG_BLOCKS, 256, 0, stream>>>(eh, eidx, WtK1, WtV1, ke, ve);
  attn_pass<<<NN, 128, 0, stream>>>(ke, ve, qA, kA, vA, row_start, srcs, hn);

  node_gemm<256, 1, true, false><<<NN / 8, 128, 0, stream>>>(
      hn, 128, kind, 64, ntype, 64, nullptr, 0,
      Ww, nullptr, nullptr, NOSKIP, 0, Wb, nullptr, nullptr,
      h, nullptr, nullptr, ln_g, ln_b, nullptr, nullptr, nullptr);

  // ---- layer 2 ----
  node_gemm<256, 3, false, false><<<NN / 8, 128, 0, stream>>>(
      kind, 64, ntype, 64, h, 128, nullptr, 0,
      Q2w, K2w, V2w, 128, 64, Q2b, K2b, V2b,
      qA, kA, vA, nullptr, nullptr, nullptr, nullptr, nullptr);

  edge_gemm<<<EG_BLOCKS, 256, 0, stream>>>(eh, eidx, WtK2, WtV2, ke, ve);
  attn_pass<<<NN, 128, 0, stream>>>(ke, ve, qA, kA, vA, row_start, srcs, hn);

  node_gemm<384, 1, true, true><<<NN / 8, 128, 0, stream>>>(
      hn, 128, h, 128, kind, 64, ntype, 64,
      W2w, nullptr, nullptr, NOSKIP, 0, W2b, nullptr, nullptr,
      h1, nullptr, nullptr, ln_g, ln_b, gate_w, gate_b, logit);

  // readout
  gstart_kernel<<<1, 128, 0, stream>>>(gid, gstart);
  readout_kernel<<<GG, 128, 0, stream>>>(h1, logit, gstart, out);
}

// Round 3
// 1022.064 us; speedup vs baseline: 1.3342x; 1.0495x over previous
//
#include <hip/hip_runtime.h>
#include <math.h>

#define NN   20000      // nodes
#define NE   640000     // edges
#define NPADN 20480     // padded node count for scan (multiple of 4096)
#define HH   128        // hidden
#define GG   64         // groups
#define INF_ 1e30f
#define FB   2560       // persistent blocks for edge_fused

typedef unsigned short u16;
typedef short bf16x8 __attribute__((ext_vector_type(8)));
typedef float f32x4 __attribute__((ext_vector_type(4)));

__device__ __forceinline__ u16 f2bf(float x) {
  union { float f; unsigned u; } c; c.f = x;
  unsigned r = c.u + 0x7FFFu + ((c.u >> 16) & 1u);
  return (u16)(r >> 16);
}
__device__ __forceinline__ float bf2f(u16 u) {
  union { unsigned u; float f; } c; c.u = ((unsigned)u) << 16;
  return c.f;
}

// ---------------- block reduction helpers (blockDim == 128) ----------------
__device__ __forceinline__ float blk_sum(float v, float* red) {
#pragma unroll
  for (int off = 32; off >= 1; off >>= 1) v += __shfl_xor(v, off);
  if ((threadIdx.x & 63) == 0) red[threadIdx.x >> 6] = v;
  __syncthreads();
  float r = red[0] + red[1];
  __syncthreads();
  return r;
}
__device__ __forceinline__ float blk_max(float v, float* red) {
#pragma unroll
  for (int off = 32; off >= 1; off >>= 1) v = fmaxf(v, __shfl_xor(v, off));
  if ((threadIdx.x & 63) == 0) red[threadIdx.x >> 6] = v;
  __syncthreads();
  float r = fmaxf(red[0], red[1]);
  __syncthreads();
  return r;
}

// ---------------- CSR construction ----------------
__global__ void zero_ints(int* p, int n) {
  int i = blockIdx.x * 256 + threadIdx.x;
  if (i < n) p[i] = 0;
}

__global__ void hist_kernel(const int* __restrict__ dst, int* __restrict__ deg) {
  int e = blockIdx.x * 256 + threadIdx.x;
  if (e < NE) atomicAdd(&deg[dst[e]], 1);
}

__global__ void scan_kernel(const int* __restrict__ deg, int* __restrict__ row_start,
                            int* __restrict__ cursor) {
  __shared__ int buf[256];
  __shared__ int carry_s;
  int t = threadIdx.x;
  if (t == 0) carry_s = 0;
  __syncthreads();
  for (int base = 0; base < NPADN; base += 4096) {
    int idx0 = base + t * 16;
    int4 a = *(const int4*)&deg[idx0];
    int4 b = *(const int4*)&deg[idx0 + 4];
    int4 c = *(const int4*)&deg[idx0 + 8];
    int4 d = *(const int4*)&deg[idx0 + 12];
    int x[16] = {a.x,a.y,a.z,a.w, b.x,b.y,b.z,b.w, c.x,c.y,c.z,c.w, d.x,d.y,d.z,d.w};
    int pre[16];
    int run = 0;
#pragma unroll
    for (int j = 0; j < 16; j++) { pre[j] = run; run += x[j]; }
    buf[t] = run;
    __syncthreads();
    int sum = run;
#pragma unroll
    for (int off = 1; off < 256; off <<= 1) {
      int addv = (t >= off) ? buf[t - off] : 0;
      __syncthreads();
      sum += addv;
      buf[t] = sum;
      __syncthreads();
    }
    int excl = sum - run;
    int carry = carry_s;
    int basev = carry + excl;
#pragma unroll
    for (int j = 0; j < 16; j++) {
      int i = idx0 + j;
      if (i < NN) { row_start[i] = basev + pre[j]; cursor[i] = basev + pre[j]; }
    }
    __syncthreads();
    if (t == 255) carry_s = carry + sum;
    __syncthreads();
  }
  if (t == 0) row_start[NN] = carry_s;
}

__global__ void scatter_kernel(const int* __restrict__ dst, const int* __restrict__ src,
                               int* __restrict__ cursor, int* __restrict__ eidx,
                               int* __restrict__ srcs) {
  int e = blockIdx.x * 256 + threadIdx.x;
  if (e < NE) {
    int d = dst[e];
    int p = atomicAdd(&cursor[d], 1);
    eidx[p] = e;
    srcs[p] = src[e];
  }
}

// ---------------- weight transpose: W[64][128] -> Wt[128][64] bf16 ----------------
__global__ void wtrans(const float* __restrict__ W, u16* __restrict__ Wt) {
  int i = blockIdx.x * 256 + threadIdx.x;
  if (i < 128 * 64) {
    int c = i >> 6, k = i & 63;
    Wt[i] = f2bf(W[k * 128 + c]);
  }
}

// ---------------- generic node GEMM: [8 nodes/block] x (K -> NCHUNK*128) ----------------
template <int K, int NCHUNK, bool DO_LN, bool DO_LOGIT>
__global__ __launch_bounds__(128) void node_gemm(
    const float* __restrict__ x0, int l0, const float* __restrict__ x1, int l1,
    const float* __restrict__ x2, int l2, const float* __restrict__ x3, int l3,
    const float* __restrict__ w0, const float* __restrict__ w1, const float* __restrict__ w2,
    int skip_at, int skip_amt,
    const float* __restrict__ b0, const float* __restrict__ b1, const float* __restrict__ b2,
    float* __restrict__ out0, float* __restrict__ out1, float* __restrict__ out2,
    const float* __restrict__ ln_g, const float* __restrict__ ln_b,
    const float* __restrict__ gate_w, const float* __restrict__ gate_b,
    float* __restrict__ logit) {
  __shared__ float xs[8][K];
  __shared__ float red[2];
  int tid = threadIdx.x;
  int n0 = blockIdx.x * 8;

  for (int idx = tid; idx < 8 * K; idx += 128) {
    int nn = idx / K, k = idx % K;
    int n = n0 + nn;
    float v;
    if (k < l0)               v = x0[n * l0 + k];
    else if (k < l0 + l1)     v = x1[n * l1 + (k - l0)];
    else if (k < l0 + l1 + l2) v = x2[n * l2 + (k - l0 - l1)];
    else                      v = x3[n * l3 + (k - l0 - l1 - l2)];
    xs[nn][k] = v;
  }
  __syncthreads();

  for (int cc = 0; cc < NCHUNK; cc++) {
    const float* W = (cc == 0) ? w0 : ((cc == 1) ? w1 : w2);
    const float* B = (cc == 0) ? b0 : ((cc == 1) ? b1 : b2);
    float acc[8];
    float bv = B[tid];
#pragma unroll
    for (int nn = 0; nn < 8; nn++) acc[nn] = bv;

    for (int j0 = 0; j0 < K; j0 += 4) {
      float w[4];
#pragma unroll
      for (int jj = 0; jj < 4; jj++) {
        int j = j0 + jj;
        int row = (cc > 0 && j >= skip_at) ? (j + skip_amt) : j;
        w[jj] = W[row * 128 + tid];
      }
#pragma unroll
      for (int nn = 0; nn < 8; nn++) {
        float4 xv = *(const float4*)&xs[nn][j0];
        acc[nn] = fmaf(xv.x, w[0], acc[nn]);
        acc[nn] = fmaf(xv.y, w[1], acc[nn]);
        acc[nn] = fmaf(xv.z, w[2], acc[nn]);
        acc[nn] = fmaf(xv.w, w[3], acc[nn]);
      }
    }

    if (!DO_LN) {
      float* outp = (cc == 0) ? out0 : ((cc == 1) ? out1 : out2);
#pragma unroll
      for (int nn = 0; nn < 8; nn++) outp[(n0 + nn) * 128 + tid] = acc[nn];
    } else {
#pragma unroll 1
      for (int nn = 0; nn < 8; nn++) {
        float val = acc[nn];
        float mean = blk_sum(val, red) * (1.0f / 128.0f);
        float dv = val - mean;
        float var = blk_sum(dv * dv, red) * (1.0f / 128.0f);
        float hv = dv * (1.0f / sqrtf(var + 1e-5f)) * ln_g[tid] + ln_b[tid];
        out0[(n0 + nn) * 128 + tid] = hv;
        if (DO_LOGIT) {
          float lg = blk_sum(hv * gate_w[tid], red);
          if (tid == 0) logit[n0 + nn] = lg + gate_b[0];
        }
      }
    }
  }
}

// ---------------- fused edge projection (MFMA) + per-dst softmax ----------------
// One wave per block, grid-stride over dst nodes. Per 16-edge tile:
//   1) gather eh rows, pack bf16, MFMA (A = Wt fragments held in VGPRs,
//      B = edge tile; D col=lane&15=edge, row=channel — round-2-validated)
//   2) write ke/ve tile to LDS, XOR-(er<<4) swizzled (2-way = free both sides)
//   3) lane owns channels (2l, 2l+1): serial over edges, alpha=exp(q*k),
//      accumulate s and h (no max-shift: |q*k| bounded, ratio shift-invariant)
__global__ __launch_bounds__(64, 2) void edge_fused(
    const float* __restrict__ eh, const int* __restrict__ eidx,
    const int* __restrict__ srcs, const int* __restrict__ row_start,
    const u16* __restrict__ WtK, const u16* __restrict__ WtV,
    const float* __restrict__ qn, const float* __restrict__ kn,
    const float* __restrict__ vn, float* __restrict__ hn) {
  __shared__ u16 lds_k[16 * 128];
  __shared__ u16 lds_v[16 * 128];
  const int lane = threadIdx.x;
  const int er = lane & 15, kg = lane >> 4;

  // weight A-fragments, held for the whole kernel (round-2-validated layout)
  bf16x8 aK[8][2], aV[8][2];
#pragma unroll
  for (int mt = 0; mt < 8; mt++)
#pragma unroll
    for (int ks = 0; ks < 2; ks++) {
      int off = (mt * 16 + er) * 64 + ks * 32 + kg * 8;
      aK[mt][ks] = *(const bf16x8*)&WtK[off];
      aV[mt][ks] = *(const bf16x8*)&WtV[off];
    }

  const int rb  = (4 * lane) & 0xF8;  // chunk base byte for channel pair (2l,2l+1)
  const int rbo = (4 * lane) & 7;     // offset within 8B chunk

  for (int n = blockIdx.x; n < NN; n += FB) {
    int rs = row_start[n], re = row_start[n + 1];
    float2 qv = *(const float2*)&qn[n * 128 + 2 * lane];
    float s0 = 0.f, s1 = 0.f, h0 = 0.f, h1 = 0.f;

    for (int t0 = rs; t0 < re; t0 += 16) {
      int cnt = min(16, re - t0);
      int e = eidx[t0 + (er < cnt ? er : 0)];
      const float* ehrow = eh + (size_t)e * 64;
      bf16x8 bE[2];
#pragma unroll
      for (int ks = 0; ks < 2; ks++) {
        float4 x0 = *(const float4*)&ehrow[ks * 32 + kg * 8];
        float4 x1 = *(const float4*)&ehrow[ks * 32 + kg * 8 + 4];
        union { u16 u[8]; bf16x8 v; } pk;
        pk.u[0] = f2bf(x0.x); pk.u[1] = f2bf(x0.y); pk.u[2] = f2bf(x0.z); pk.u[3] = f2bf(x0.w);
        pk.u[4] = f2bf(x1.x); pk.u[5] = f2bf(x1.y); pk.u[6] = f2bf(x1.z); pk.u[7] = f2bf(x1.w);
        bE[ks] = pk.v;
      }

      f32x4 acc[8];
      // K projection
#pragma unroll
      for (int mt = 0; mt < 8; mt++) acc[mt] = (f32x4){0.f, 0.f, 0.f, 0.f};
#pragma unroll
      for (int mt = 0; mt < 8; mt++)
#pragma unroll
        for (int ks = 0; ks < 2; ks++)
          acc[mt] = __builtin_amdgcn_mfma_f32_16x16x32_bf16(aK[mt][ks], bE[ks], acc[mt], 0, 0, 0);
#pragma unroll
      for (int mt = 0; mt < 8; mt++) {
        int col = mt * 32 + kg * 8;              // byte within row for channels mt*16+kg*4..+3
        uint2 w;
        w.x = (unsigned)f2bf(acc[mt][0]) | ((unsigned)f2bf(acc[mt][1]) << 16);
        w.y = (unsigned)f2bf(acc[mt][2]) | ((unsigned)f2bf(acc[mt][3]) << 16);
        *(uint2*)((char*)lds_k + er * 256 + (col ^ (er << 4))) = w;
      }
      // V projection (reuse acc)
#pragma unroll
      for (int mt = 0; mt < 8; mt++) acc[mt] = (f32x4){0.f, 0.f, 0.f, 0.f};
#pragma unroll
      for (int mt = 0; mt < 8; mt++)
#pragma unroll
        for (int ks = 0; ks < 2; ks++)
          acc[mt] = __builtin_amdgcn_mfma_f32_16x16x32_bf16(aV[mt][ks], bE[ks], acc[mt], 0, 0, 0);
#pragma unroll
      for (int mt = 0; mt < 8; mt++) {
        int col = mt * 32 + kg * 8;
        uint2 w;
        w.x = (unsigned)f2bf(acc[mt][0]) | ((unsigned)f2bf(acc[mt][1]) << 16);
        w.y = (unsigned)f2bf(acc[mt][2]) | ((unsigned)f2bf(acc[mt][3]) << 16);
        *(uint2*)((char*)lds_v + er * 256 + (col ^ (er << 4))) = w;
      }
      __syncthreads();

      for (int i = 0; i < cnt; i++) {
        int sv = srcs[t0 + i];
        float2 knv = *(const float2*)&kn[sv * 128 + 2 * lane];
        float2 vnv = *(const float2*)&vn[sv * 128 + 2 * lane];
        int sb = i * 256 + ((rb ^ (i << 4)) | rbo);
        unsigned wk = *(const unsigned*)((const char*)lds_k + sb);
        unsigned wv = *(const unsigned*)((const char*)lds_v + sb);
        float kv0 = knv.x + bf2f((u16)(wk & 0xFFFF));
        float kv1 = knv.y + bf2f((u16)(wk >> 16));
        float vv0 = vnv.x + bf2f((u16)(wv & 0xFFFF));
        float vv1 = vnv.y + bf2f((u16)(wv >> 16));
        float p0 = __expf(qv.x * kv0);
        float p1 = __expf(qv.y * kv1);
        s0 += p0; s1 += p1;
        h0 = fmaf(p0, vv0, h0);
        h1 = fmaf(p1, vv1, h1);
      }
      __syncthreads();
    }

    float2 o;
    o.x = (re > rs) ? h0 / s0 : 0.f;
    o.y = (re > rs) ? h1 / s1 : 0.f;
    *(float2*)&hn[n * 128 + 2 * lane] = o;
  }
}

// ---------------- readout ----------------
__global__ void gstart_kernel(const int* __restrict__ gid, int* __restrict__ gstart) {
  int g = threadIdx.x;
  if (g <= GG) {
    int lo = 0, hi = NN;
    while (lo < hi) {
      int mid = (lo + hi) >> 1;
      if (gid[mid] < g) lo = mid + 1; else hi = mid;
    }
    gstart[g] = lo;
  }
}

__global__ __launch_bounds__(128) void readout_kernel(
    const float* __restrict__ h1, const float* __restrict__ logit,
    const int* __restrict__ gstart, float* __restrict__ out) {
  __shared__ float red[2];
  int g = blockIdx.x, tid = threadIdx.x;
  int s0 = gstart[g], s1 = gstart[g + 1];

  float mx = -INF_;
  for (int i = s0 + tid; i < s1; i += 128) mx = fmaxf(mx, logit[i]);
  mx = blk_max(mx, red);

  float sum = 0.0f;
  for (int i = s0 + tid; i < s1; i += 128) sum += __expf(logit[i] - mx);
  sum = blk_sum(sum, red);

  float acc = 0.0f;
  for (int i = s0; i < s1; i++) {
    float w = __expf(logit[i] - mx);
    acc = fmaf(w, h1[i * 128 + tid], acc);
  }
  out[g * 128 + tid] = (s1 > s0) ? (acc / sum) : 0.0f;
}

// ---------------- launcher ----------------
extern "C" void kernel_launch(void* const* d_in, const int* in_sizes, int n_in,
                              void* d_out, int out_size, void* d_ws, size_t ws_size,
                              hipStream_t stream) {
  const float* kind  = (const float*)d_in[0];
  const float* ntype = (const float*)d_in[1];
  const float* eh    = (const float*)d_in[2];
  const float* Qw = (const float*)d_in[3];  const float* Qb = (const float*)d_in[4];
  const float* Kw = (const float*)d_in[5];  const float* Kb = (const float*)d_in[6];
  const float* Vw = (const float*)d_in[7];  const float* Vb = (const float*)d_in[8];
  const float* Ww = (const float*)d_in[9];  const float* Wb = (const float*)d_in[10];
  const float* Q2w = (const float*)d_in[11]; const float* Q2b = (const float*)d_in[12];
  const float* K2w = (const float*)d_in[13]; const float* K2b = (const float*)d_in[14];
  const float* V2w = (const float*)d_in[15]; const float* V2b = (const float*)d_in[16];
  const float* W2w = (const float*)d_in[17]; const float* W2b = (const float*)d_in[18];
  const float* ln_g = (const float*)d_in[19]; const float* ln_b = (const float*)d_in[20];
  const float* gate_w = (const float*)d_in[21]; const float* gate_b = (const float*)d_in[22];
  const int* src = (const int*)d_in[23];
  const int* dst = (const int*)d_in[24];
  const int* gid = (const int*)d_in[25];
  float* out = (float*)d_out;

  char* wp = (char*)d_ws;
  auto alloc = [&](size_t bytes) {
    void* p = (void*)wp;
    wp += (bytes + 255) & ~(size_t)255;
    return p;
  };
  float* qA = (float*)alloc((size_t)NN * HH * 4);
  float* kA = (float*)alloc((size_t)NN * HH * 4);
  float* vA = (float*)alloc((size_t)NN * HH * 4);
  float* hn = (float*)alloc((size_t)NN * HH * 4);
  float* h  = (float*)alloc((size_t)NN * HH * 4);
  float* h1 = (float*)alloc((size_t)NN * HH * 4);
  float* logit = (float*)alloc((size_t)NN * 4);
  u16* WtK1 = (u16*)alloc((size_t)128 * 64 * 2);
  u16* WtV1 = (u16*)alloc((size_t)128 * 64 * 2);
  u16* WtK2 = (u16*)alloc((size_t)128 * 64 * 2);
  u16* WtV2 = (u16*)alloc((size_t)128 * 64 * 2);
  int* deg       = (int*)alloc((size_t)NPADN * 4);
  int* row_start = (int*)alloc((size_t)(NN + 1) * 4);
  int* cursor    = (int*)alloc((size_t)NN * 4);
  int* eidx      = (int*)alloc((size_t)NE * 4);
  int* srcs      = (int*)alloc((size_t)NE * 4);
  int* gstart    = (int*)alloc((size_t)(GG + 1) * 4);

  const int NOSKIP = 1 << 30;

  // CSR
  zero_ints<<<(NPADN + 255) / 256, 256, 0, stream>>>(deg, NPADN);
  hist_kernel<<<(NE + 255) / 256, 256, 0, stream>>>(dst, deg);
  scan_kernel<<<1, 256, 0, stream>>>(deg, row_start, cursor);
  scatter_kernel<<<(NE + 255) / 256, 256, 0, stream>>>(dst, src, cursor, eidx, srcs);

  // weight transposes for edge GEMMs (rows 128..191 = eh part of K/V weights)
  wtrans<<<32, 256, 0, stream>>>(Kw + 128 * 128, WtK1);
  wtrans<<<32, 256, 0, stream>>>(Vw + 128 * 128, WtV1);
  wtrans<<<32, 256, 0, stream>>>(K2w + 128 * 128, WtK2);
  wtrans<<<32, 256, 0, stream>>>(V2w + 128 * 128, WtV2);

  // ---- layer 1 ----
  node_gemm<128, 3, false, false><<<NN / 8, 128, 0, stream>>>(
      kind, 64, ntype, 64, nullptr, 0, nullptr, 0,
      Qw, Kw, Vw, NOSKIP, 0, Qb, Kb, Vb,
      qA, kA, vA, nullptr, nullptr, nullptr, nullptr, nullptr);

  edge_fused<<<FB, 64, 0, stream>>>(eh, eidx, srcs, row_start, WtK1, WtV1,
                                    qA, kA, vA, hn);

  node_gemm<256, 1, true, false><<<NN / 8, 128, 0, stream>>>(
      hn, 128, kind, 64, ntype, 64, nullptr, 0,
      Ww, nullptr, nullptr, NOSKIP, 0, Wb, nullptr, nullptr,
      h, nullptr, nullptr, ln_g, ln_b, nullptr, nullptr, nullptr);

  // ---- layer 2 ----
  node_gemm<256, 3, false, false><<<NN / 8, 128, 0, stream>>>(
      kind, 64, ntype, 64, h, 128, nullptr, 0,
      Q2w, K2w, V2w, 128, 64, Q2b, K2b, V2b,
      qA, kA, vA, nullptr, nullptr, nullptr, nullptr, nullptr);

  edge_fused<<<FB, 64, 0, stream>>>(eh, eidx, srcs, row_start, WtK2, WtV2,
                                    qA, kA, vA, hn);

  node_gemm<384, 1, true, true><<<NN / 8, 128, 0, stream>>>(
      hn, 128, h, 128, kind, 64, ntype, 64,
      W2w, nullptr, nullptr, NOSKIP, 0, W2b, nullptr, nullptr,
      h1, nullptr, nullptr, ln_g, ln_b, gate_w, gate_b, logit);

  // readout
  gstart_kernel<<<1, 128, 0, stream>>>(gid, gstart);
  readout_kernel<<<GG, 128, 0, stream>>>(h1, logit, gstart, out);
}

// Round 4
// 831.172 us; speedup vs baseline: 1.6406x; 1.2297x over previous
//
#include <hip/hip_runtime.h>
#include <math.h>

#define NN   20000      // nodes
#define NE   640000     // edges
#define NPADN 20480     // padded node count for scan (multiple of 4096)
#define HH   128        // hidden
#define GG   64         // groups
#define INF_ 1e30f
#define FB2  4096       // persistent blocks for edge_fused

typedef unsigned short u16;
typedef short bf16x8 __attribute__((ext_vector_type(8)));
typedef float f32x4 __attribute__((ext_vector_type(4)));

__device__ __forceinline__ u16 f2bf(float x) {
  union { float f; unsigned u; } c; c.f = x;
  unsigned r = c.u + 0x7FFFu + ((c.u >> 16) & 1u);
  return (u16)(r >> 16);
}

// ---------------- block reduction helpers (blockDim == 128) ----------------
__device__ __forceinline__ float blk_sum(float v, float* red) {
#pragma unroll
  for (int off = 32; off >= 1; off >>= 1) v += __shfl_xor(v, off);
  if ((threadIdx.x & 63) == 0) red[threadIdx.x >> 6] = v;
  __syncthreads();
  float r = red[0] + red[1];
  __syncthreads();
  return r;
}
__device__ __forceinline__ float blk_max(float v, float* red) {
#pragma unroll
  for (int off = 32; off >= 1; off >>= 1) v = fmaxf(v, __shfl_xor(v, off));
  if ((threadIdx.x & 63) == 0) red[threadIdx.x >> 6] = v;
  __syncthreads();
  float r = fmaxf(red[0], red[1]);
  __syncthreads();
  return r;
}

// ---------------- CSR construction ----------------
__global__ void zero_ints(int* p, int n) {
  int i = blockIdx.x * 256 + threadIdx.x;
  if (i < n) p[i] = 0;
}

__global__ void hist_kernel(const int* __restrict__ dst, int* __restrict__ deg) {
  int e = blockIdx.x * 256 + threadIdx.x;
  if (e < NE) atomicAdd(&deg[dst[e]], 1);
}

__global__ void scan_kernel(const int* __restrict__ deg, int* __restrict__ row_start,
                            int* __restrict__ cursor) {
  __shared__ int buf[256];
  __shared__ int carry_s;
  int t = threadIdx.x;
  if (t == 0) carry_s = 0;
  __syncthreads();
  for (int base = 0; base < NPADN; base += 4096) {
    int idx0 = base + t * 16;
    int4 a = *(const int4*)&deg[idx0];
    int4 b = *(const int4*)&deg[idx0 + 4];
    int4 c = *(const int4*)&deg[idx0 + 8];
    int4 d = *(const int4*)&deg[idx0 + 12];
    int x[16] = {a.x,a.y,a.z,a.w, b.x,b.y,b.z,b.w, c.x,c.y,c.z,c.w, d.x,d.y,d.z,d.w};
    int pre[16];
    int run = 0;
#pragma unroll
    for (int j = 0; j < 16; j++) { pre[j] = run; run += x[j]; }
    buf[t] = run;
    __syncthreads();
    int sum = run;
#pragma unroll
    for (int off = 1; off < 256; off <<= 1) {
      int addv = (t >= off) ? buf[t - off] : 0;
      __syncthreads();
      sum += addv;
      buf[t] = sum;
      __syncthreads();
    }
    int excl = sum - run;
    int carry = carry_s;
    int basev = carry + excl;
#pragma unroll
    for (int j = 0; j < 16; j++) {
      int i = idx0 + j;
      if (i < NN) { row_start[i] = basev + pre[j]; cursor[i] = basev + pre[j]; }
    }
    __syncthreads();
    if (t == 255) carry_s = carry + sum;
    __syncthreads();
  }
  if (t == 0) row_start[NN] = carry_s;
}

__global__ void scatter_kernel(const int* __restrict__ dst, const int* __restrict__ src,
                               int* __restrict__ cursor, int* __restrict__ eidx,
                               int* __restrict__ srcs) {
  int e = blockIdx.x * 256 + threadIdx.x;
  if (e < NE) {
    int d = dst[e];
    int p = atomicAdd(&cursor[d], 1);
    eidx[p] = e;
    srcs[p] = src[e];
  }
}

// ---------------- weight transpose: W[64][128] -> Wt[128][64] bf16 ----------------
__global__ void wtrans(const float* __restrict__ W, u16* __restrict__ Wt) {
  int i = blockIdx.x * 256 + threadIdx.x;
  if (i < 128 * 64) {
    int c = i >> 6, k = i & 63;
    Wt[i] = f2bf(W[k * 128 + c]);
  }
}

// ---------------- generic node GEMM: [8 nodes/block] x (K -> NCHUNK*128) ----------------
template <int K, int NCHUNK, bool DO_LN, bool DO_LOGIT>
__global__ __launch_bounds__(128) void node_gemm(
    const float* __restrict__ x0, int l0, const float* __restrict__ x1, int l1,
    const float* __restrict__ x2, int l2, const float* __restrict__ x3, int l3,
    const float* __restrict__ w0, const float* __restrict__ w1, const float* __restrict__ w2,
    int skip_at, int skip_amt,
    const float* __restrict__ b0, const float* __restrict__ b1, const float* __restrict__ b2,
    float* __restrict__ out0, float* __restrict__ out1, float* __restrict__ out2,
    const float* __restrict__ ln_g, const float* __restrict__ ln_b,
    const float* __restrict__ gate_w, const float* __restrict__ gate_b,
    float* __restrict__ logit) {
  __shared__ float xs[8][K];
  __shared__ float red[2];
  int tid = threadIdx.x;
  int n0 = blockIdx.x * 8;

  for (int idx = tid; idx < 8 * K; idx += 128) {
    int nn = idx / K, k = idx % K;
    int n = n0 + nn;
    float v;
    if (k < l0)               v = x0[n * l0 + k];
    else if (k < l0 + l1)     v = x1[n * l1 + (k - l0)];
    else if (k < l0 + l1 + l2) v = x2[n * l2 + (k - l0 - l1)];
    else                      v = x3[n * l3 + (k - l0 - l1 - l2)];
    xs[nn][k] = v;
  }
  __syncthreads();

  for (int cc = 0; cc < NCHUNK; cc++) {
    const float* W = (cc == 0) ? w0 : ((cc == 1) ? w1 : w2);
    const float* B = (cc == 0) ? b0 : ((cc == 1) ? b1 : b2);
    float acc[8];
    float bv = B[tid];
#pragma unroll
    for (int nn = 0; nn < 8; nn++) acc[nn] = bv;

    for (int j0 = 0; j0 < K; j0 += 4) {
      float w[4];
#pragma unroll
      for (int jj = 0; jj < 4; jj++) {
        int j = j0 + jj;
        int row = (cc > 0 && j >= skip_at) ? (j + skip_amt) : j;
        w[jj] = W[row * 128 + tid];
      }
#pragma unroll
      for (int nn = 0; nn < 8; nn++) {
        float4 xv = *(const float4*)&xs[nn][j0];
        acc[nn] = fmaf(xv.x, w[0], acc[nn]);
        acc[nn] = fmaf(xv.y, w[1], acc[nn]);
        acc[nn] = fmaf(xv.z, w[2], acc[nn]);
        acc[nn] = fmaf(xv.w, w[3], acc[nn]);
      }
    }

    if (!DO_LN) {
      float* outp = (cc == 0) ? out0 : ((cc == 1) ? out1 : out2);
#pragma unroll
      for (int nn = 0; nn < 8; nn++) outp[(n0 + nn) * 128 + tid] = acc[nn];
    } else {
#pragma unroll 1
      for (int nn = 0; nn < 8; nn++) {
        float val = acc[nn];
        float mean = blk_sum(val, red) * (1.0f / 128.0f);
        float dv = val - mean;
        float var = blk_sum(dv * dv, red) * (1.0f / 128.0f);
        float hv = dv * (1.0f / sqrtf(var + 1e-5f)) * ln_g[tid] + ln_b[tid];
        out0[(n0 + nn) * 128 + tid] = hv;
        if (DO_LOGIT) {
          float lg = blk_sum(hv * gate_w[tid], red);
          if (tid == 0) logit[n0 + nn] = lg + gate_b[0];
        }
      }
    }
  }
}

// ---------------- fused edge projection (MFMA) + per-dst softmax, no LDS ----------------
// Block = 256 threads = 4 independent waves = 4 channel-quarters (32 ch each)
// of one node. Lane (er,kg) of quarter qw owns edge-slot er and channels
// c(mtl,j) = qw*32 + mtl*16 + kg*4 + j. MFMA D-layout (col=lane&15=edge,
// row=channel, round-2-validated) matches this directly: no transpose, no
// LDS, no barriers. S,H accumulate in-lane across tiles; one shfl_xor
// reduction over er-lanes per node at the end.
__global__ __launch_bounds__(256, 3) void edge_fused(
    const float* __restrict__ eh, const int* __restrict__ eidx,
    const int* __restrict__ srcs, const int* __restrict__ row_start,
    const u16* __restrict__ WtK, const u16* __restrict__ WtV,
    const float* __restrict__ qn, const float* __restrict__ kn,
    const float* __restrict__ vn, float* __restrict__ hn) {
  const int lane = threadIdx.x & 63;
  const int qw = threadIdx.x >> 6;       // channel quarter 0..3
  const int er = lane & 15, kg = lane >> 4;
  const int cbase = qw * 32 + kg * 4;    // first channel (mtl=0, j=0)

  // A-fragments for this wave's 32 channels (2 16-row tiles), validated layout
  bf16x8 aK[2][2], aV[2][2];
#pragma unroll
  for (int mtl = 0; mtl < 2; mtl++)
#pragma unroll
    for (int ks = 0; ks < 2; ks++) {
      int row = (qw * 2 + mtl) * 16 + er;
      int off = row * 64 + ks * 32 + kg * 8;
      aK[mtl][ks] = *(const bf16x8*)&WtK[off];
      aV[mtl][ks] = *(const bf16x8*)&WtV[off];
    }

  for (int n = blockIdx.x; n < NN; n += FB2) {
    int rs = row_start[n], re = row_start[n + 1];
    float4 q0 = *(const float4*)&qn[n * 128 + cbase];
    float4 q1 = *(const float4*)&qn[n * 128 + cbase + 16];
    f32x4 S0 = {0.f,0.f,0.f,0.f}, S1 = {0.f,0.f,0.f,0.f};
    f32x4 H0 = {0.f,0.f,0.f,0.f}, H1 = {0.f,0.f,0.f,0.f};

    for (int t0 = rs; t0 < re; t0 += 16) {
      int cnt = re - t0; cnt = cnt > 16 ? 16 : cnt;
      int idx = t0 + (er < cnt ? er : cnt - 1);
      int e = eidx[idx];
      int sv = srcs[idx];
      // gathers (issued early; independent of MFMA chain)
      const float* knp = &kn[sv * 128 + cbase];
      const float* vnp = &vn[sv * 128 + cbase];
      float4 kn0 = *(const float4*)knp;
      float4 kn1 = *(const float4*)(knp + 16);
      float4 vn0 = *(const float4*)vnp;
      float4 vn1 = *(const float4*)(vnp + 16);

      const float* ehrow = eh + (size_t)e * 64;
      bf16x8 bE[2];
#pragma unroll
      for (int ks = 0; ks < 2; ks++) {
        float4 x0 = *(const float4*)&ehrow[ks * 32 + kg * 8];
        float4 x1 = *(const float4*)&ehrow[ks * 32 + kg * 8 + 4];
        union { u16 u[8]; bf16x8 v; } pk;
        pk.u[0] = f2bf(x0.x); pk.u[1] = f2bf(x0.y); pk.u[2] = f2bf(x0.z); pk.u[3] = f2bf(x0.w);
        pk.u[4] = f2bf(x1.x); pk.u[5] = f2bf(x1.y); pk.u[6] = f2bf(x1.z); pk.u[7] = f2bf(x1.w);
        bE[ks] = pk.v;
      }

      f32x4 aK0 = {0.f,0.f,0.f,0.f}, aK1 = {0.f,0.f,0.f,0.f};
      f32x4 aV0 = {0.f,0.f,0.f,0.f}, aV1 = {0.f,0.f,0.f,0.f};
#pragma unroll
      for (int ks = 0; ks < 2; ks++) {
        aK0 = __builtin_amdgcn_mfma_f32_16x16x32_bf16(aK[0][ks], bE[ks], aK0, 0, 0, 0);
        aV0 = __builtin_amdgcn_mfma_f32_16x16x32_bf16(aV[0][ks], bE[ks], aV0, 0, 0, 0);
        aK1 = __builtin_amdgcn_mfma_f32_16x16x32_bf16(aK[1][ks], bE[ks], aK1, 0, 0, 0);
        aV1 = __builtin_amdgcn_mfma_f32_16x16x32_bf16(aV[1][ks], bE[ks], aV1, 0, 0, 0);
      }

      float pmask = (er < cnt) ? 1.0f : 0.0f;
      float kna0[4] = {kn0.x, kn0.y, kn0.z, kn0.w};
      float kna1[4] = {kn1.x, kn1.y, kn1.z, kn1.w};
      float vna0[4] = {vn0.x, vn0.y, vn0.z, vn0.w};
      float vna1[4] = {vn1.x, vn1.y, vn1.z, vn1.w};
      float qa0[4]  = {q0.x, q0.y, q0.z, q0.w};
      float qa1[4]  = {q1.x, q1.y, q1.z, q1.w};
#pragma unroll
      for (int j = 0; j < 4; j++) {
        float p = __expf(qa0[j] * (kna0[j] + aK0[j])) * pmask;
        S0[j] += p;
        H0[j] = fmaf(p, vna0[j] + aV0[j], H0[j]);
      }
#pragma unroll
      for (int j = 0; j < 4; j++) {
        float p = __expf(qa1[j] * (kna1[j] + aK1[j])) * pmask;
        S1[j] += p;
        H1[j] = fmaf(p, vna1[j] + aV1[j], H1[j]);
      }
    }

    // reduce over the 16 er-lanes (bits 0..3 of lane id)
#pragma unroll
    for (int off = 1; off <= 8; off <<= 1) {
#pragma unroll
      for (int j = 0; j < 4; j++) {
        S0[j] += __shfl_xor(S0[j], off);
        H0[j] += __shfl_xor(H0[j], off);
        S1[j] += __shfl_xor(S1[j], off);
        H1[j] += __shfl_xor(H1[j], off);
      }
    }
    if (er == 0) {
      float4 o0, o1;
      if (re > rs) {
        o0.x = H0[0]/S0[0]; o0.y = H0[1]/S0[1]; o0.z = H0[2]/S0[2]; o0.w = H0[3]/S0[3];
        o1.x = H1[0]/S1[0]; o1.y = H1[1]/S1[1]; o1.z = H1[2]/S1[2]; o1.w = H1[3]/S1[3];
      } else {
        o0.x = o0.y = o0.z = o0.w = 0.f;
        o1.x = o1.y = o1.z = o1.w = 0.f;
      }
      *(float4*)&hn[n * 128 + cbase] = o0;
      *(float4*)&hn[n * 128 + cbase + 16] = o1;
    }
  }
}

// ---------------- readout ----------------
__global__ void gstart_kernel(const int* __restrict__ gid, int* __restrict__ gstart) {
  int g = threadIdx.x;
  if (g <= GG) {
    int lo = 0, hi = NN;
    while (lo < hi) {
      int mid = (lo + hi) >> 1;
      if (gid[mid] < g) lo = mid + 1; else hi = mid;
    }
    gstart[g] = lo;
  }
}

__global__ __launch_bounds__(128) void readout_kernel(
    const float* __restrict__ h1, const float* __restrict__ logit,
    const int* __restrict__ gstart, float* __restrict__ out) {
  __shared__ float red[2];
  int g = blockIdx.x, tid = threadIdx.x;
  int s0 = gstart[g], s1 = gstart[g + 1];

  float mx = -INF_;
  for (int i = s0 + tid; i < s1; i += 128) mx = fmaxf(mx, logit[i]);
  mx = blk_max(mx, red);

  float sum = 0.0f;
  for (int i = s0 + tid; i < s1; i += 128) sum += __expf(logit[i] - mx);
  sum = blk_sum(sum, red);

  float acc = 0.0f;
  for (int i = s0; i < s1; i++) {
    float w = __expf(logit[i] - mx);
    acc = fmaf(w, h1[i * 128 + tid], acc);
  }
  out[g * 128 + tid] = (s1 > s0) ? (acc / sum) : 0.0f;
}

// ---------------- launcher ----------------
extern "C" void kernel_launch(void* const* d_in, const int* in_sizes, int n_in,
                              void* d_out, int out_size, void* d_ws, size_t ws_size,
                              hipStream_t stream) {
  const float* kind  = (const float*)d_in[0];
  const float* ntype = (const float*)d_in[1];
  const float* eh    = (const float*)d_in[2];
  const float* Qw = (const float*)d_in[3];  const float* Qb = (const float*)d_in[4];
  const float* Kw = (const float*)d_in[5];  const float* Kb = (const float*)d_in[6];
  const float* Vw = (const float*)d_in[7];  const float* Vb = (const float*)d_in[8];
  const float* Ww = (const float*)d_in[9];  const float* Wb = (const float*)d_in[10];
  const float* Q2w = (const float*)d_in[11]; const float* Q2b = (const float*)d_in[12];
  const float* K2w = (const float*)d_in[13]; const float* K2b = (const float*)d_in[14];
  const float* V2w = (const float*)d_in[15]; const float* V2b = (const float*)d_in[16];
  const float* W2w = (const float*)d_in[17]; const float* W2b = (const float*)d_in[18];
  const float* ln_g = (const float*)d_in[19]; const float* ln_b = (const float*)d_in[20];
  const float* gate_w = (const float*)d_in[21]; const float* gate_b = (const float*)d_in[22];
  const int* src = (const int*)d_in[23];
  const int* dst = (const int*)d_in[24];
  const int* gid = (const int*)d_in[25];
  float* out = (float*)d_out;

  char* wp = (char*)d_ws;
  auto alloc = [&](size_t bytes) {
    void* p = (void*)wp;
    wp += (bytes + 255) & ~(size_t)255;
    return p;
  };
  float* qA = (float*)alloc((size_t)NN * HH * 4);
  float* kA = (float*)alloc((size_t)NN * HH * 4);
  float* vA = (float*)alloc((size_t)NN * HH * 4);
  float* hn = (float*)alloc((size_t)NN * HH * 4);
  float* h  = (float*)alloc((size_t)NN * HH * 4);
  float* h1 = (float*)alloc((size_t)NN * HH * 4);
  float* logit = (float*)alloc((size_t)NN * 4);
  u16* WtK1 = (u16*)alloc((size_t)128 * 64 * 2);
  u16* WtV1 = (u16*)alloc((size_t)128 * 64 * 2);
  u16* WtK2 = (u16*)alloc((size_t)128 * 64 * 2);
  u16* WtV2 = (u16*)alloc((size_t)128 * 64 * 2);
  int* deg       = (int*)alloc((size_t)NPADN * 4);
  int* row_start = (int*)alloc((size_t)(NN + 1) * 4);
  int* cursor    = (int*)alloc((size_t)NN * 4);
  int* eidx      = (int*)alloc((size_t)NE * 4);
  int* srcs      = (int*)alloc((size_t)NE * 4);
  int* gstart    = (int*)alloc((size_t)(GG + 1) * 4);

  const int NOSKIP = 1 << 30;

  // CSR
  zero_ints<<<(NPADN + 255) / 256, 256, 0, stream>>>(deg, NPADN);
  hist_kernel<<<(NE + 255) / 256, 256, 0, stream>>>(dst, deg);
  scan_kernel<<<1, 256, 0, stream>>>(deg, row_start, cursor);
  scatter_kernel<<<(NE + 255) / 256, 256, 0, stream>>>(dst, src, cursor, eidx, srcs);

  // weight transposes for edge GEMMs (rows 128..191 = eh part of K/V weights)
  wtrans<<<32, 256, 0, stream>>>(Kw + 128 * 128, WtK1);
  wtrans<<<32, 256, 0, stream>>>(Vw + 128 * 128, WtV1);
  wtrans<<<32, 256, 0, stream>>>(K2w + 128 * 128, WtK2);
  wtrans<<<32, 256, 0, stream>>>(V2w + 128 * 128, WtV2);

  // ---- layer 1 ----
  node_gemm<128, 3, false, false><<<NN / 8, 128, 0, stream>>>(
      kind, 64, ntype, 64, nullptr, 0, nullptr, 0,
      Qw, Kw, Vw, NOSKIP, 0, Qb, Kb, Vb,
      qA, kA, vA, nullptr, nullptr, nullptr, nullptr, nullptr);

  edge_fused<<<FB2, 256, 0, stream>>>(eh, eidx, srcs, row_start, WtK1, WtV1,
                                      qA, kA, vA, hn);

  node_gemm<256, 1, true, false><<<NN / 8, 128, 0, stream>>>(
      hn, 128, kind, 64, ntype, 64, nullptr, 0,
      Ww, nullptr, nullptr, NOSKIP, 0, Wb, nullptr, nullptr,
      h, nullptr, nullptr, ln_g, ln_b, nullptr, nullptr, nullptr);

  // ---- layer 2 ----
  node_gemm<256, 3, false, false><<<NN / 8, 128, 0, stream>>>(
      kind, 64, ntype, 64, h, 128, nullptr, 0,
      Q2w, K2w, V2w, 128, 64, Q2b, K2b, V2b,
      qA, kA, vA, nullptr, nullptr, nullptr, nullptr, nullptr);

  edge_fused<<<FB2, 256, 0, stream>>>(eh, eidx, srcs, row_start, WtK2, WtV2,
                                      qA, kA, vA, hn);

  node_gemm<384, 1, true, true><<<NN / 8, 128, 0, stream>>>(
      hn, 128, h, 128, kind, 64, ntype, 64,
      W2w, nullptr, nullptr, NOSKIP, 0, W2b, nullptr, nullptr,
      h1, nullptr, nullptr, ln_g, ln_b, gate_w, gate_b, logit);

  // readout
  gstart_kernel<<<1, 128, 0, stream>>>(gid, gstart);
  readout_kernel<<<GG, 128, 0, stream>>>(h1, logit, gstart, out);
}

// Round 5
// 750.588 us; speedup vs baseline: 1.8168x; 1.1074x over previous
//
#include <hip/hip_runtime.h>
#include <math.h>

#define NN   20000      // nodes
#define NE   640000     // edges
#define NPADN 20480     // padded node count for scan (multiple of 4096)
#define HH   128        // hidden
#define GG   64         // groups
#define INF_ 1e30f
#define FB2  4096       // persistent blocks for edge_fused

typedef unsigned short u16;
typedef short bf16x8 __attribute__((ext_vector_type(8)));
typedef float f32x4 __attribute__((ext_vector_type(4)));

struct KMap { int colb[12]; };   // XM column base per 32-wide k-block

__device__ __forceinline__ u16 f2bf(float x) {
  union { float f; unsigned u; } c; c.f = x;
  unsigned r = c.u + 0x7FFFu + ((c.u >> 16) & 1u);
  return (u16)(r >> 16);
}

// ---------------- block reduction helpers (blockDim == 128) ----------------
__device__ __forceinline__ float blk_sum(float v, float* red) {
#pragma unroll
  for (int off = 32; off >= 1; off >>= 1) v += __shfl_xor(v, off);
  if ((threadIdx.x & 63) == 0) red[threadIdx.x >> 6] = v;
  __syncthreads();
  float r = red[0] + red[1];
  __syncthreads();
  return r;
}
__device__ __forceinline__ float blk_max(float v, float* red) {
#pragma unroll
  for (int off = 32; off >= 1; off >>= 1) v = fmaxf(v, __shfl_xor(v, off));
  if ((threadIdx.x & 63) == 0) red[threadIdx.x >> 6] = v;
  __syncthreads();
  float r = fmaxf(red[0], red[1]);
  __syncthreads();
  return r;
}

// ---------------- CSR construction ----------------
__global__ void zero_ints(int* p, int n) {
  int i = blockIdx.x * 256 + threadIdx.x;
  if (i < n) p[i] = 0;
}

__global__ void hist_kernel(const int* __restrict__ dst, int* __restrict__ deg) {
  int e = blockIdx.x * 256 + threadIdx.x;
  if (e < NE) atomicAdd(&deg[dst[e]], 1);
}

__global__ void scan_kernel(const int* __restrict__ deg, int* __restrict__ row_start,
                            int* __restrict__ cursor) {
  __shared__ int buf[256];
  __shared__ int carry_s;
  int t = threadIdx.x;
  if (t == 0) carry_s = 0;
  __syncthreads();
  for (int base = 0; base < NPADN; base += 4096) {
    int idx0 = base + t * 16;
    int4 a = *(const int4*)&deg[idx0];
    int4 b = *(const int4*)&deg[idx0 + 4];
    int4 c = *(const int4*)&deg[idx0 + 8];
    int4 d = *(const int4*)&deg[idx0 + 12];
    int x[16] = {a.x,a.y,a.z,a.w, b.x,b.y,b.z,b.w, c.x,c.y,c.z,c.w, d.x,d.y,d.z,d.w};
    int pre[16];
    int run = 0;
#pragma unroll
    for (int j = 0; j < 16; j++) { pre[j] = run; run += x[j]; }
    buf[t] = run;
    __syncthreads();
    int sum = run;
#pragma unroll
    for (int off = 1; off < 256; off <<= 1) {
      int addv = (t >= off) ? buf[t - off] : 0;
      __syncthreads();
      sum += addv;
      buf[t] = sum;
      __syncthreads();
    }
    int excl = sum - run;
    int carry = carry_s;
    int basev = carry + excl;
#pragma unroll
    for (int j = 0; j < 16; j++) {
      int i = idx0 + j;
      if (i < NN) { row_start[i] = basev + pre[j]; cursor[i] = basev + pre[j]; }
    }
    __syncthreads();
    if (t == 255) carry_s = carry + sum;
    __syncthreads();
  }
  if (t == 0) row_start[NN] = carry_s;
}

__global__ void scatter_kernel(const int* __restrict__ dst, const int* __restrict__ src,
                               int* __restrict__ cursor, int* __restrict__ eidx,
                               int* __restrict__ srcs) {
  int e = blockIdx.x * 256 + threadIdx.x;
  if (e < NE) {
    int d = dst[e];
    int p = atomicAdd(&cursor[d], 1);
    eidx[p] = e;
    srcs[p] = src[e];
  }
}

// ---------------- prepack: XM[:,0:128] = bf16([kind|ntype]) ----------------
__global__ void pack_x(const float* __restrict__ kind, const float* __restrict__ ntype,
                       u16* __restrict__ XM) {
  int i = blockIdx.x * 256 + threadIdx.x;
  if (i < NN * 128) {
    int n = i >> 7, c = i & 127;
    float v = (c < 64) ? kind[n * 64 + c] : ntype[n * 64 + (c - 64)];
    XM[(size_t)n * 512 + c] = f2bf(v);
  }
}

// ---------------- prepack: Wt[c][k] = bf16(W[rowmap(k)][c]) ----------------
__global__ void pack_wt(const float* __restrict__ W, u16* __restrict__ dst, int K,
                        int skip_at, int skip_amt) {
  int i = blockIdx.x * 256 + threadIdx.x;
  if (i < 128 * K) {
    int c = i / K, k = i - c * K;
    int row = (k < skip_at) ? k : k + skip_amt;
    dst[i] = f2bf(W[row * 128 + c]);
  }
}

// ---------------- edge-weight transpose: W[64][128] -> Wt[128][64] bf16 ----------------
__global__ void wtrans(const float* __restrict__ W, u16* __restrict__ Wt) {
  int i = blockIdx.x * 256 + threadIdx.x;
  if (i < 128 * 64) {
    int c = i >> 6, k = i & 63;
    Wt[i] = f2bf(W[k * 128 + c]);
  }
}

// ---------------- MFMA node GEMM ----------------
// Block = 4 waves x 16 rows. A = XM rows (lane er loads row row0+er, k-slice
// kg*8 within the 32-k block mapped by kmap.colb). B = Wt cols (lane er loads
// col er+16*nt). Same lane-k-map on A and B -> exact for any internal k
// permutation (round-2-validated). D: row = node = kg*4+reg, col = er+16*nt.
// Epilogue: bias (+ LayerNorm + gate logit) in f32; LN reduces over the 16
// er-lanes via shfl_xor 1/2/4/8.
template <int KSTEPS, int NCHUNK, bool DO_LN, bool DO_LOGIT>
__global__ __launch_bounds__(256) void mfma_gemm(
    const u16* __restrict__ XM, const u16* __restrict__ Wt, KMap kmap,
    const float* __restrict__ b0, const float* __restrict__ b1, const float* __restrict__ b2,
    float* __restrict__ o0, float* __restrict__ o1, float* __restrict__ o2,
    u16* __restrict__ outbf,
    const float* __restrict__ ln_g, const float* __restrict__ ln_b,
    const float* __restrict__ gate_w, const float* __restrict__ gate_b,
    float* __restrict__ logit) {
  const int lane = threadIdx.x & 63;
  const int wv = threadIdx.x >> 6;
  const int er = lane & 15, kg = lane >> 4;
  const int row0 = (blockIdx.x * 4 + wv) * 16;
  if (row0 >= NN) return;                       // wave-uniform, no barriers used
  const int arow = (row0 + er < NN) ? row0 + er : NN - 1;
  constexpr int K = KSTEPS * 32;
  constexpr int NT = NCHUNK * 8;
  const u16* aptr = XM + (size_t)arow * 512 + kg * 8;
  const u16* wptr = Wt + (size_t)er * K + kg * 8;

  f32x4 acc[NT];
#pragma unroll
  for (int i = 0; i < NT; i++) acc[i] = (f32x4){0.f, 0.f, 0.f, 0.f};

#pragma unroll
  for (int ks = 0; ks < KSTEPS; ks++) {
    bf16x8 a = *(const bf16x8*)&aptr[kmap.colb[ks]];
#pragma unroll
    for (int nt = 0; nt < NT; nt++) {
      bf16x8 b = *(const bf16x8*)&wptr[(size_t)nt * 16 * K + ks * 32];
      acc[nt] = __builtin_amdgcn_mfma_f32_16x16x32_bf16(a, b, acc[nt], 0, 0, 0);
    }
  }

  if (!DO_LN) {
#pragma unroll
    for (int c = 0; c < NCHUNK; c++) {
      float* op = (c == 0) ? o0 : (c == 1) ? o1 : o2;
      const float* bp = (c == 0) ? b0 : (c == 1) ? b1 : b2;
#pragma unroll
      for (int t = 0; t < 8; t++) {
        int col = er + 16 * t;
        float bv = bp[col];
#pragma unroll
        for (int r = 0; r < 4; r++) {
          int m = row0 + kg * 4 + r;
          if (m < NN) op[(size_t)m * 128 + col] = acc[c * 8 + t][r] + bv;
        }
      }
    }
  } else {
    float g[8], bb[8], gw[8];
#pragma unroll
    for (int t = 0; t < 8; t++) {
      int col = er + 16 * t;
      float bv = b0[col];
#pragma unroll
      for (int r = 0; r < 4; r++) acc[t][r] += bv;
      g[t] = ln_g[col]; bb[t] = ln_b[col];
      if (DO_LOGIT) gw[t] = gate_w[col];
    }
    float gb0 = DO_LOGIT ? gate_b[0] : 0.f;
#pragma unroll
    for (int r = 0; r < 4; r++) {
      float s = 0.f;
#pragma unroll
      for (int t = 0; t < 8; t++) s += acc[t][r];
#pragma unroll
      for (int off = 1; off <= 8; off <<= 1) s += __shfl_xor(s, off);
      float mean = s * (1.0f / 128.0f);
      float v = 0.f;
#pragma unroll
      for (int t = 0; t < 8; t++) { float d = acc[t][r] - mean; v = fmaf(d, d, v); }
#pragma unroll
      for (int off = 1; off <= 8; off <<= 1) v += __shfl_xor(v, off);
      float rstd = 1.0f / sqrtf(v * (1.0f / 128.0f) + 1e-5f);
      int m = row0 + kg * 4 + r;
      float lg = 0.f;
      float hv[8];
#pragma unroll
      for (int t = 0; t < 8; t++) {
        hv[t] = (acc[t][r] - mean) * rstd * g[t] + bb[t];
        if (DO_LOGIT) lg = fmaf(hv[t], gw[t], lg);
      }
      if (m < NN) {
        if (outbf) {
#pragma unroll
          for (int t = 0; t < 8; t++) outbf[(size_t)m * 512 + er + 16 * t] = f2bf(hv[t]);
        } else {
#pragma unroll
          for (int t = 0; t < 8; t++) o0[(size_t)m * 128 + er + 16 * t] = hv[t];
        }
      }
      if (DO_LOGIT) {
#pragma unroll
        for (int off = 1; off <= 8; off <<= 1) lg += __shfl_xor(lg, off);
        if (er == 0 && m < NN) logit[m] = lg + gb0;
      }
    }
  }
}

// ---------------- fused edge projection (MFMA) + per-dst softmax, no LDS ----------------
// Block = 256 threads = 4 waves = 4 channel-quarters of one node. Writes the
// per-node attention output directly as bf16 into XM (stride 512).
__global__ __launch_bounds__(256, 3) void edge_fused(
    const float* __restrict__ eh, const int* __restrict__ eidx,
    const int* __restrict__ srcs, const int* __restrict__ row_start,
    const u16* __restrict__ WtK, const u16* __restrict__ WtV,
    const float* __restrict__ qn, const float* __restrict__ kn,
    const float* __restrict__ vn, u16* __restrict__ xmh) {
  const int lane = threadIdx.x & 63;
  const int qw = threadIdx.x >> 6;       // channel quarter 0..3
  const int er = lane & 15, kg = lane >> 4;
  const int cbase = qw * 32 + kg * 4;    // first channel (mtl=0, j=0)

  bf16x8 aK[2][2], aV[2][2];
#pragma unroll
  for (int mtl = 0; mtl < 2; mtl++)
#pragma unroll
    for (int ks = 0; ks < 2; ks++) {
      int row = (qw * 2 + mtl) * 16 + er;
      int off = row * 64 + ks * 32 + kg * 8;
      aK[mtl][ks] = *(const bf16x8*)&WtK[off];
      aV[mtl][ks] = *(const bf16x8*)&WtV[off];
    }

  for (int n = blockIdx.x; n < NN; n += FB2) {
    int rs = row_start[n], re = row_start[n + 1];
    float4 q0 = *(const float4*)&qn[n * 128 + cbase];
    float4 q1 = *(const float4*)&qn[n * 128 + cbase + 16];
    f32x4 S0 = {0.f,0.f,0.f,0.f}, S1 = {0.f,0.f,0.f,0.f};
    f32x4 H0 = {0.f,0.f,0.f,0.f}, H1 = {0.f,0.f,0.f,0.f};

    for (int t0 = rs; t0 < re; t0 += 16) {
      int cnt = re - t0; cnt = cnt > 16 ? 16 : cnt;
      int idx = t0 + (er < cnt ? er : cnt - 1);
      int e = eidx[idx];
      int sv = srcs[idx];
      const float* knp = &kn[sv * 128 + cbase];
      const float* vnp = &vn[sv * 128 + cbase];
      float4 kn0 = *(const float4*)knp;
      float4 kn1 = *(const float4*)(knp + 16);
      float4 vn0 = *(const float4*)vnp;
      float4 vn1 = *(const float4*)(vnp + 16);

      const float* ehrow = eh + (size_t)e * 64;
      bf16x8 bE[2];
#pragma unroll
      for (int ks = 0; ks < 2; ks++) {
        float4 x0 = *(const float4*)&ehrow[ks * 32 + kg * 8];
        float4 x1 = *(const float4*)&ehrow[ks * 32 + kg * 8 + 4];
        union { u16 u[8]; bf16x8 v; } pk;
        pk.u[0] = f2bf(x0.x); pk.u[1] = f2bf(x0.y); pk.u[2] = f2bf(x0.z); pk.u[3] = f2bf(x0.w);
        pk.u[4] = f2bf(x1.x); pk.u[5] = f2bf(x1.y); pk.u[6] = f2bf(x1.z); pk.u[7] = f2bf(x1.w);
        bE[ks] = pk.v;
      }

      f32x4 aK0 = {0.f,0.f,0.f,0.f}, aK1 = {0.f,0.f,0.f,0.f};
      f32x4 aV0 = {0.f,0.f,0.f,0.f}, aV1 = {0.f,0.f,0.f,0.f};
#pragma unroll
      for (int ks = 0; ks < 2; ks++) {
        aK0 = __builtin_amdgcn_mfma_f32_16x16x32_bf16(aK[0][ks], bE[ks], aK0, 0, 0, 0);
        aV0 = __builtin_amdgcn_mfma_f32_16x16x32_bf16(aV[0][ks], bE[ks], aV0, 0, 0, 0);
        aK1 = __builtin_amdgcn_mfma_f32_16x16x32_bf16(aK[1][ks], bE[ks], aK1, 0, 0, 0);
        aV1 = __builtin_amdgcn_mfma_f32_16x16x32_bf16(aV[1][ks], bE[ks], aV1, 0, 0, 0);
      }

      float pmask = (er < cnt) ? 1.0f : 0.0f;
      float kna0[4] = {kn0.x, kn0.y, kn0.z, kn0.w};
      float kna1[4] = {kn1.x, kn1.y, kn1.z, kn1.w};
      float vna0[4] = {vn0.x, vn0.y, vn0.z, vn0.w};
      float vna1[4] = {vn1.x, vn1.y, vn1.z, vn1.w};
      float qa0[4]  = {q0.x, q0.y, q0.z, q0.w};
      float qa1[4]  = {q1.x, q1.y, q1.z, q1.w};
#pragma unroll
      for (int j = 0; j < 4; j++) {
        float p = __expf(qa0[j] * (kna0[j] + aK0[j])) * pmask;
        S0[j] += p;
        H0[j] = fmaf(p, vna0[j] + aV0[j], H0[j]);
      }
#pragma unroll
      for (int j = 0; j < 4; j++) {
        float p = __expf(qa1[j] * (kna1[j] + aK1[j])) * pmask;
        S1[j] += p;
        H1[j] = fmaf(p, vna1[j] + aV1[j], H1[j]);
      }
    }

#pragma unroll
    for (int off = 1; off <= 8; off <<= 1) {
#pragma unroll
      for (int j = 0; j < 4; j++) {
        S0[j] += __shfl_xor(S0[j], off);
        H0[j] += __shfl_xor(H0[j], off);
        S1[j] += __shfl_xor(S1[j], off);
        H1[j] += __shfl_xor(H1[j], off);
      }
    }
    if (er == 0) {
      uint2 p0, p1;
      if (re > rs) {
        p0.x = (unsigned)f2bf(H0[0]/S0[0]) | ((unsigned)f2bf(H0[1]/S0[1]) << 16);
        p0.y = (unsigned)f2bf(H0[2]/S0[2]) | ((unsigned)f2bf(H0[3]/S0[3]) << 16);
        p1.x = (unsigned)f2bf(H1[0]/S1[0]) | ((unsigned)f2bf(H1[1]/S1[1]) << 16);
        p1.y = (unsigned)f2bf(H1[2]/S1[2]) | ((unsigned)f2bf(H1[3]/S1[3]) << 16);
      } else { p0.x = p0.y = p1.x = p1.y = 0u; }
      *(uint2*)&xmh[(size_t)n * 512 + cbase] = p0;
      *(uint2*)&xmh[(size_t)n * 512 + cbase + 16] = p1;
    }
  }
}

// ---------------- readout ----------------
__global__ void gstart_kernel(const int* __restrict__ gid, int* __restrict__ gstart) {
  int g = threadIdx.x;
  if (g <= GG) {
    int lo = 0, hi = NN;
    while (lo < hi) {
      int mid = (lo + hi) >> 1;
      if (gid[mid] < g) lo = mid + 1; else hi = mid;
    }
    gstart[g] = lo;
  }
}

__global__ __launch_bounds__(128) void readout_kernel(
    const float* __restrict__ h1, const float* __restrict__ logit,
    const int* __restrict__ gstart, float* __restrict__ out) {
  __shared__ float red[2];
  int g = blockIdx.x, tid = threadIdx.x;
  int s0 = gstart[g], s1 = gstart[g + 1];

  float mx = -INF_;
  for (int i = s0 + tid; i < s1; i += 128) mx = fmaxf(mx, logit[i]);
  mx = blk_max(mx, red);

  float sum = 0.0f;
  for (int i = s0 + tid; i < s1; i += 128) sum += __expf(logit[i] - mx);
  sum = blk_sum(sum, red);

  float acc = 0.0f;
  for (int i = s0; i < s1; i++) {
    float w = __expf(logit[i] - mx);
    acc = fmaf(w, h1[i * 128 + tid], acc);
  }
  out[g * 128 + tid] = (s1 > s0) ? (acc / sum) : 0.0f;
}

// ---------------- launcher ----------------
extern "C" void kernel_launch(void* const* d_in, const int* in_sizes, int n_in,
                              void* d_out, int out_size, void* d_ws, size_t ws_size,
                              hipStream_t stream) {
  const float* kind  = (const float*)d_in[0];
  const float* ntype = (const float*)d_in[1];
  const float* eh    = (const float*)d_in[2];
  const float* Qw = (const float*)d_in[3];  const float* Qb = (const float*)d_in[4];
  const float* Kw = (const float*)d_in[5];  const float* Kb = (const float*)d_in[6];
  const float* Vw = (const float*)d_in[7];  const float* Vb = (const float*)d_in[8];
  const float* Ww = (const float*)d_in[9];  const float* Wb = (const float*)d_in[10];
  const float* Q2w = (const float*)d_in[11]; const float* Q2b = (const float*)d_in[12];
  const float* K2w = (const float*)d_in[13]; const float* K2b = (const float*)d_in[14];
  const float* V2w = (const float*)d_in[15]; const float* V2b = (const float*)d_in[16];
  const float* W2w = (const float*)d_in[17]; const float* W2b = (const float*)d_in[18];
  const float* ln_g = (const float*)d_in[19]; const float* ln_b = (const float*)d_in[20];
  const float* gate_w = (const float*)d_in[21]; const float* gate_b = (const float*)d_in[22];
  const int* src = (const int*)d_in[23];
  const int* dst = (const int*)d_in[24];
  const int* gid = (const int*)d_in[25];
  float* out = (float*)d_out;

  char* wp = (char*)d_ws;
  auto alloc = [&](size_t bytes) {
    void* p = (void*)wp;
    wp += (bytes + 255) & ~(size_t)255;
    return p;
  };
  u16* XM = (u16*)alloc((size_t)NN * 512 * 2);          // [kind|ntype | hn | h | hn2] bf16
  float* qA = (float*)alloc((size_t)NN * HH * 4);
  float* kA = (float*)alloc((size_t)NN * HH * 4);
  float* vA = (float*)alloc((size_t)NN * HH * 4);
  float* h1 = (float*)alloc((size_t)NN * HH * 4);
  float* logit = (float*)alloc((size_t)NN * 4);
  u16* Wt1 = (u16*)alloc((size_t)384 * 128 * 2);
  u16* Wt2 = (u16*)alloc((size_t)128 * 256 * 2);
  u16* Wt3 = (u16*)alloc((size_t)384 * 256 * 2);
  u16* Wt4 = (u16*)alloc((size_t)128 * 384 * 2);
  u16* WtK1 = (u16*)alloc((size_t)128 * 64 * 2);
  u16* WtV1 = (u16*)alloc((size_t)128 * 64 * 2);
  u16* WtK2 = (u16*)alloc((size_t)128 * 64 * 2);
  u16* WtV2 = (u16*)alloc((size_t)128 * 64 * 2);
  int* deg       = (int*)alloc((size_t)NPADN * 4);
  int* row_start = (int*)alloc((size_t)(NN + 1) * 4);
  int* cursor    = (int*)alloc((size_t)NN * 4);
  int* eidx      = (int*)alloc((size_t)NE * 4);
  int* srcs      = (int*)alloc((size_t)NE * 4);
  int* gstart    = (int*)alloc((size_t)(GG + 1) * 4);

  const int NB = 1 << 30;  // no skip

  // CSR
  zero_ints<<<(NPADN + 255) / 256, 256, 0, stream>>>(deg, NPADN);
  hist_kernel<<<(NE + 255) / 256, 256, 0, stream>>>(dst, deg);
  scan_kernel<<<1, 256, 0, stream>>>(deg, row_start, cursor);
  scatter_kernel<<<(NE + 255) / 256, 256, 0, stream>>>(dst, src, cursor, eidx, srcs);

  // prepack activations + weights
  pack_x<<<(NN * 128 + 255) / 256, 256, 0, stream>>>(kind, ntype, XM);
  pack_wt<<<(128 * 128 + 255) / 256, 256, 0, stream>>>(Qw, Wt1, 128, NB, 0);
  pack_wt<<<(128 * 128 + 255) / 256, 256, 0, stream>>>(Kw, Wt1 + 128 * 128, 128, NB, 0);
  pack_wt<<<(128 * 128 + 255) / 256, 256, 0, stream>>>(Vw, Wt1 + 2 * 128 * 128, 128, NB, 0);
  pack_wt<<<(128 * 256 + 255) / 256, 256, 0, stream>>>(Ww, Wt2, 256, NB, 0);
  pack_wt<<<(128 * 256 + 255) / 256, 256, 0, stream>>>(Q2w, Wt3, 256, NB, 0);
  pack_wt<<<(128 * 256 + 255) / 256, 256, 0, stream>>>(K2w, Wt3 + 128 * 256, 256, 128, 64);
  pack_wt<<<(128 * 256 + 255) / 256, 256, 0, stream>>>(V2w, Wt3 + 2 * 128 * 256, 256, 128, 64);
  pack_wt<<<(128 * 384 + 255) / 256, 256, 0, stream>>>(W2w, Wt4, 384, NB, 0);
  wtrans<<<32, 256, 0, stream>>>(Kw + 128 * 128, WtK1);
  wtrans<<<32, 256, 0, stream>>>(Vw + 128 * 128, WtV1);
  wtrans<<<32, 256, 0, stream>>>(K2w + 128 * 128, WtK2);
  wtrans<<<32, 256, 0, stream>>>(V2w + 128 * 128, WtV2);

  KMap km1{}, km2{}, km3{}, km4{};
  for (int b = 0; b < 4; b++)  km1.colb[b] = 32 * b;                       // [kind|ntype]
  for (int b = 0; b < 8; b++)  km2.colb[b] = (b < 4) ? 128 + 32 * b : 32 * (b - 4);   // [hn | kind|ntype]
  for (int b = 0; b < 8; b++)  km3.colb[b] = (b < 4) ? 32 * b : 256 + 32 * (b - 4);   // [kind|ntype | h]
  for (int b = 0; b < 12; b++) km4.colb[b] = (b < 4) ? 384 + 32 * b
                                       : (b < 8) ? 256 + 32 * (b - 4) : 32 * (b - 8); // [hn2 | h | kind|ntype]

  const int GB = (NN + 63) / 64;

  // ---- layer 1 ----
  mfma_gemm<4, 3, false, false><<<GB, 256, 0, stream>>>(
      XM, Wt1, km1, Qb, Kb, Vb, qA, kA, vA, nullptr,
      nullptr, nullptr, nullptr, nullptr, nullptr);

  edge_fused<<<FB2, 256, 0, stream>>>(eh, eidx, srcs, row_start, WtK1, WtV1,
                                      qA, kA, vA, XM + 128);

  mfma_gemm<8, 1, true, false><<<GB, 256, 0, stream>>>(
      XM, Wt2, km2, Wb, nullptr, nullptr, nullptr, nullptr, nullptr, XM + 256,
      ln_g, ln_b, nullptr, nullptr, nullptr);

  // ---- layer 2 ----
  mfma_gemm<8, 3, false, false><<<GB, 256, 0, stream>>>(
      XM, Wt3, km3, Q2b, K2b, V2b, qA, kA, vA, nullptr,
      nullptr, nullptr, nullptr, nullptr, nullptr);

  edge_fused<<<FB2, 256, 0, stream>>>(eh, eidx, srcs, row_start, WtK2, WtV2,
                                      qA, kA, vA, XM + 384);

  mfma_gemm<12, 1, true, true><<<GB, 256, 0, stream>>>(
      XM, Wt4, km4, W2b, nullptr, nullptr, h1, nullptr, nullptr, nullptr,
      ln_g, ln_b, gate_w, gate_b, logit);

  // readout
  gstart_kernel<<<1, 128, 0, stream>>>(gid, gstart);
  readout_kernel<<<GG, 128, 0, stream>>>(h1, logit, gstart, out);
}